// Round 1
// 544.544 us; speedup vs baseline: 1.0426x; 1.0426x over previous
//
#include <hip/hip_runtime.h>

typedef unsigned short u16;
typedef unsigned int   u32;
typedef __bf16 bf16x8 __attribute__((ext_vector_type(8)));
typedef float  f32x4  __attribute__((ext_vector_type(4)));
typedef float  f32x16 __attribute__((ext_vector_type(16)));

#define B_  8
#define T_  2048
#define D_  1024
#define H_  8
#define C_  64
#define DV_ 128
#define M_  (B_*T_)   // 16384
#define L_  128       // scan chunk length
#define NC_ (T_/L_)   // 16 chunks
#define TS_ 8         // timesteps per sO reduction sub-block (pass2)

__device__ __forceinline__ u16 f2bf(float f){
  u32 u = __float_as_uint(f);
  u32 r = (u + 0x7fffu + ((u >> 16) & 1u)) >> 16;   // RNE
  return (u16)r;
}
__device__ __forceinline__ float bf2f(u16 u){
  return __uint_as_float(((u32)u) << 16);
}

// ---------------- LayerNorm: x (M,1024) f32 -> xn bf16 ----------------
__global__ __launch_bounds__(256) void ln_kernel(
    const float* __restrict__ x, const float* __restrict__ gamma,
    const float* __restrict__ beta, u16* __restrict__ xnb){
  const int m = blockIdx.x;
  const int tid = threadIdx.x;
  const int wave = tid >> 6, lane = tid & 63;
  const float* xr = x + (size_t)m * D_;
  float4 xv = *(const float4*)&xr[tid*4];
  float s = xv.x + xv.y + xv.z + xv.w;
  #pragma unroll
  for (int off = 32; off > 0; off >>= 1) s += __shfl_xor(s, off, 64);
  __shared__ float red[8];
  if (lane == 0) red[wave] = s;
  __syncthreads();
  float mu = (red[0]+red[1]+red[2]+red[3]) * (1.f/1024.f);
  float dx = xv.x-mu, dy = xv.y-mu, dz = xv.z-mu, dw = xv.w-mu;
  float ss = dx*dx + dy*dy + dz*dz + dw*dw;
  #pragma unroll
  for (int off = 32; off > 0; off >>= 1) ss += __shfl_xor(ss, off, 64);
  if (lane == 0) red[4+wave] = ss;
  __syncthreads();
  float var = (red[4]+red[5]+red[6]+red[7]) * (1.f/1024.f);
  float rs = rsqrtf(var + 1e-5f);
  float4 g  = *(const float4*)&gamma[tid*4];
  float4 bb = *(const float4*)&beta[tid*4];
  ushort4 o4;
  o4.x = f2bf(dx*rs*g.x + bb.x);
  o4.y = f2bf(dy*rs*g.y + bb.y);
  o4.z = f2bf(dz*rs*g.z + bb.z);
  o4.w = f2bf(dw*rs*g.w + bb.w);
  *(ushort4*)&xnb[(size_t)m*D_ + tid*4] = o4;
}

// ------------- weight prep: convert/concat/transpose to bf16 -------------
__global__ __launch_bounds__(256) void prep_weights(
    const float* __restrict__ Wq, const float* __restrict__ Wk,
    const float* __restrict__ Wv, const float* __restrict__ Wa,
    const float* __restrict__ Qc, const float* __restrict__ Vc,
    const float* __restrict__ Wo,
    u16* __restrict__ Wcatb, u16* __restrict__ QcTb,
    u16* __restrict__ VcTb,  u16* __restrict__ Wob){
  int idx = blockIdx.x * 256 + threadIdx.x;
  if (idx < 720896){                       // 704*1024
    int r = idx >> 10, col = idx & 1023;
    float v;
    if (r < 64)       v = Wq[(size_t)r*1024 + col];
    else if (r < 128) v = Wk[(size_t)(r-64)*1024 + col];
    else if (r < 192) v = Wv[(size_t)(r-128)*1024 + col];
    else              v = Wa[(size_t)(r-192)*1024 + col];
    Wcatb[idx] = f2bf(v);
  } else if (idx < 753664){                // +512*64
    int i = idx - 720896;
    int n = i >> 6, c = i & 63; int h = n >> 6, e = n & 63;
    QcTb[i] = f2bf(Qc[((size_t)h*64 + c)*64 + e]);
  } else if (idx < 819200){                // +1024*64
    int i = idx - 753664;
    int n = i >> 6, c = i & 63; int h = n >> 7, d = n & 127;
    VcTb[i] = f2bf(Vc[((size_t)h*64 + c)*128 + d]);
  } else if (idx < 1867776){               // +1024*1024
    int i = idx - 819200;
    Wob[i] = f2bf(Wo[i]);
  }
}

// ------------- generic bf16 MFMA GEMM: C = A[M,K] @ Bw[N,K]^T (+res) -------
__global__ __launch_bounds__(256) void gemm_bf16(
    const u16* __restrict__ A, const u16* __restrict__ Bw,
    float* __restrict__ C, const float* __restrict__ res,
    u16* __restrict__ Cb, int N, int K){
  __shared__ u16 As[128][36];
  __shared__ u16 Bs[64][36];
  const int tid = threadIdx.x;
  const int wave = tid >> 6;
  const int lane = tid & 63;
  const int q  = lane >> 4;
  const int mr = lane & 15;
  const int m0 = blockIdx.x * 128;
  const int n0 = blockIdx.y * 64;

  union FragU { u32 u[4]; bf16x8 v; };
  f32x4 zero = {0.f, 0.f, 0.f, 0.f};
  f32x4 acc[2][4];
  #pragma unroll
  for (int i = 0; i < 2; i++)
    #pragma unroll
    for (int j = 0; j < 4; j++) acc[i][j] = zero;

  for (int k0 = 0; k0 < K; k0 += 32){
    #pragma unroll
    for (int p = 0; p < 2; ++p){
      int ch = p*256 + tid;
      int r = ch >> 2, c4 = ch & 3;
      const uint4 val = *(const uint4*)(&A[(size_t)(m0 + r)*K + k0 + c4*8]);
      u32* dst = (u32*)&As[r][c4*8];
      dst[0]=val.x; dst[1]=val.y; dst[2]=val.z; dst[3]=val.w;
    }
    {
      int r = tid >> 2, c4 = tid & 3;
      const uint4 val = *(const uint4*)(&Bw[(size_t)(n0 + r)*K + k0 + c4*8]);
      u32* dst = (u32*)&Bs[r][c4*8];
      dst[0]=val.x; dst[1]=val.y; dst[2]=val.z; dst[3]=val.w;
    }
    __syncthreads();
    bf16x8 afr[2], bfr[4];
    #pragma unroll
    for (int mt = 0; mt < 2; mt++){
      const u32* p = (const u32*)&As[wave*32 + mt*16 + mr][q*8];
      FragU f; f.u[0]=p[0]; f.u[1]=p[1]; f.u[2]=p[2]; f.u[3]=p[3];
      afr[mt] = f.v;
    }
    #pragma unroll
    for (int nt = 0; nt < 4; nt++){
      const u32* p = (const u32*)&Bs[nt*16 + mr][q*8];
      FragU f; f.u[0]=p[0]; f.u[1]=p[1]; f.u[2]=p[2]; f.u[3]=p[3];
      bfr[nt] = f.v;
    }
    #pragma unroll
    for (int mt = 0; mt < 2; mt++)
      #pragma unroll
      for (int nt = 0; nt < 4; nt++)
        acc[mt][nt] = __builtin_amdgcn_mfma_f32_16x16x32_bf16(
            afr[mt], bfr[nt], acc[mt][nt], 0, 0, 0);
    __syncthreads();
  }

  #pragma unroll
  for (int mt = 0; mt < 2; mt++)
    #pragma unroll
    for (int nt = 0; nt < 4; nt++)
      #pragma unroll
      for (int r = 0; r < 4; r++){
        int row = m0 + wave*32 + mt*16 + q*4 + r;
        int col = n0 + nt*16 + mr;
        size_t idx = (size_t)row * N + col;
        float v = acc[mt][nt][r];
        if (res) v += res[idx];
        if (Cb) Cb[idx] = f2bf(v);
        else    C[idx] = v;
      }
}

// ------------- split proj (M x 704) -------------
__global__ __launch_bounds__(256) void split_proj(
    const float* __restrict__ proj, const float* __restrict__ Wab,
    u16* __restrict__ qlatb, float* __restrict__ knf,
    u16* __restrict__ vlatb, float* __restrict__ alphaf){
  const int m = blockIdx.x * 4 + (threadIdx.x >> 6);
  const int lane = threadIdx.x & 63;
  const float* pr = proj + (size_t)m * 704;
  qlatb[(size_t)m*64 + lane] = f2bf(pr[lane]);
  float kv = pr[64 + lane];
  float ss = kv * kv;
  #pragma unroll
  for (int off = 32; off > 0; off >>= 1) ss += __shfl_xor(ss, off, 64);
  float nrm = fmaxf(sqrtf(ss), 1e-12f);
  knf[(size_t)m*64 + lane] = kv / nrm;
  vlatb[(size_t)m*64 + lane] = f2bf(pr[128 + lane]);
  #pragma unroll
  for (int j = 0; j < 8; j++){
    int jj = j*64 + lane;
    float av = pr[192 + jj] + Wab[jj];
    alphaf[(size_t)m*512 + jj] = 1.f / (1.f + expf(-av));
  }
}

// ===================== blocked two-pass gated scan =====================
// 512 threads: thread (g = tid>>7 in [0,4), d = tid&127). Each thread holds
// S[16] = state channels [g*16, g*16+16) for column d.
//
// KEY CHANGE vs prior round: a/k/q are WAVE-UNIFORM (g, t uniform per wave).
// Previous version broadcast-read them from LDS: 12 ds_read_b128/wave/tt
// (~150 LDS-unit cyc) vs only ~96 VALU cyc -> LDS-pipe-bound (VALUBusy 62%,
// 0 bank conflicts because broadcasts). Now they are fetched with
// s_load_dwordx16 into SGPRs (v_fma takes one SGPR operand), so the hot
// loop has ~zero LDS reads. pass1 needs no LDS/barriers at all.
// "=&s" earlyclobber: SMEM results return asynchronously; outputs must not
// alias the later s_loads' address registers.

__device__ __forceinline__ void sload2(const float* ap, const float* kp,
                                       f32x16& a16, f32x16& k16){
  asm volatile("s_load_dwordx16 %0, %2, 0x0\n\t"
               "s_load_dwordx16 %1, %3, 0x0\n\t"
               "s_waitcnt lgkmcnt(0)"
               : "=&s"(a16), "=&s"(k16)
               : "s"(ap), "s"(kp));
}
__device__ __forceinline__ void sload3(const float* ap, const float* kp,
                                       const float* qp,
                                       f32x16& a16, f32x16& k16, f32x16& q16){
  asm volatile("s_load_dwordx16 %0, %3, 0x0\n\t"
               "s_load_dwordx16 %1, %4, 0x0\n\t"
               "s_load_dwordx16 %2, %5, 0x0\n\t"
               "s_waitcnt lgkmcnt(0)"
               : "=&s"(a16), "=&s"(k16), "=&s"(q16)
               : "s"(ap), "s"(kp), "s"(qp));
}

__global__ __launch_bounds__(512, 8) void scan_pass1(
    const float* __restrict__ knf, const u16* __restrict__ vb,
    const float* __restrict__ alphaf,
    float* __restrict__ Sbuf, float* __restrict__ btot){
  const int ch = blockIdx.x;        // 0..NC_-2 (last chunk's state unused)
  const int bh = blockIdx.y;
  const int b = bh >> 3, h = bh & 7;
  const int tid = threadIdx.x;
  const int g = __builtin_amdgcn_readfirstlane(tid >> 7);  // wave-uniform
  const int d = tid & 127;
  const int t0 = ch * L_;

  const float* kp = knf    + ((size_t)(b*T_ + t0))*64  + g*16;
  const float* ap = alphaf + ((size_t)(b*T_ + t0))*512 + h*64 + g*16;
  const u16*   vp = vb     + ((size_t)(b*T_ + t0))*1024 + h*128 + d;

  float S[16];
  #pragma unroll
  for (int i = 0; i < 16; i++) S[i] = 0.f;
  float bt = 1.f;

  for (int t = 0; t < L_; t++){
    float vd = bf2f(vp[0]);
    float al = 1.f;
    if (d < 16) al = ap[d];          // per-lane alpha for the btot product
    f32x16 a16, k16;
    sload2(ap, kp, a16, k16);
    #pragma unroll
    for (int i = 0; i < 16; i++)
      S[i] = a16[i]*S[i] + k16[i]*vd;
    bt *= al;
    kp += 64; ap += 512; vp += 1024;
  }

  float* Sl = Sbuf + ((size_t)bh*NC_ + ch) * (64*128);
  #pragma unroll
  for (int i = 0; i < 16; i++) Sl[(size_t)(g*16+i)*128 + d] = S[i];
  if (d < 16) btot[((size_t)bh*NC_ + ch)*64 + g*16 + d] = bt;
}

// in-place: Sbuf[ch] (local states) -> Sbuf[ch] (prefix init states)
__global__ __launch_bounds__(256) void scan_combine(
    float* __restrict__ Sbuf, const float* __restrict__ btot){
  const int bh = blockIdx.x;
  const int tid = threadIdx.x;
  float S[32];
  #pragma unroll
  for (int i = 0; i < 32; i++) S[i] = 0.f;
  float*       Sb  = Sbuf + (size_t)bh*NC_*8192;
  const float* btb = btot + (size_t)bh*NC_*64;
  for (int j = 0; j < NC_; j++){
    if (j < NC_-1){
      #pragma unroll
      for (int i = 0; i < 32; i++){
        int e = i*256 + tid;
        float loc = Sb[(size_t)j*8192 + e];          // read local BEFORE overwrite
        float bv  = btb[j*64 + (e >> 7)];
        Sb[(size_t)j*8192 + e] = S[i];               // write prefix state
        S[i] = bv * S[i] + loc;
      }
    } else {
      #pragma unroll
      for (int i = 0; i < 32; i++) Sb[(size_t)j*8192 + i*256 + tid] = S[i];
    }
  }
}

__global__ __launch_bounds__(512, 8) void scan_pass2(
    const float* __restrict__ qf, const float* __restrict__ knf,
    const u16* __restrict__ vb, const float* __restrict__ alphaf,
    const float* __restrict__ Sbuf, u16* __restrict__ ob){
  const int ch = blockIdx.x;        // 0..NC_-1
  const int bh = blockIdx.y;
  const int b = bh >> 3, h = bh & 7;
  const int tid = threadIdx.x;
  const int g = __builtin_amdgcn_readfirstlane(tid >> 7);  // wave-uniform
  const int d = tid & 127;
  const int t0 = ch * L_;
  __shared__ __align__(16) float sO[4][TS_][128];   // 16 KB

  const float* qp = qf     + ((size_t)(b*T_ + t0))*512 + h*64 + g*16;
  const float* kp = knf    + ((size_t)(b*T_ + t0))*64  + g*16;
  const float* ap = alphaf + ((size_t)(b*T_ + t0))*512 + h*64 + g*16;
  const u16*   vp = vb     + ((size_t)(b*T_ + t0))*1024 + h*128 + d;
  u16*         obase = ob  + ((size_t)(b*T_ + t0))*1024 + h*128;

  float S[16];
  const float* Si = Sbuf + ((size_t)bh*NC_ + ch) * (64*128);
  #pragma unroll
  for (int i = 0; i < 16; i++) S[i] = Si[(size_t)(g*16+i)*128 + d];

  for (int sb = 0; sb < L_/TS_; sb++){
    #pragma unroll
    for (int tt = 0; tt < TS_; tt++){
      float vd = bf2f(vp[0]);
      f32x16 a16, k16, q16;
      sload3(ap, kp, qp, a16, k16, q16);
      float o0 = 0.f, o1 = 0.f, o2 = 0.f, o3 = 0.f;  // break the fma chain
      #pragma unroll
      for (int i = 0; i < 16; i += 4){
        S[i+0] = a16[i+0]*S[i+0] + k16[i+0]*vd;  o0 += S[i+0]*q16[i+0];
        S[i+1] = a16[i+1]*S[i+1] + k16[i+1]*vd;  o1 += S[i+1]*q16[i+1];
        S[i+2] = a16[i+2]*S[i+2] + k16[i+2]*vd;  o2 += S[i+2]*q16[i+2];
        S[i+3] = a16[i+3]*S[i+3] + k16[i+3]*vd;  o3 += S[i+3]*q16[i+3];
      }
      sO[g][tt][d] = (o0+o1)+(o2+o3);
      kp += 64; ap += 512; qp += 512; vp += 1024;
    }
    __syncthreads();
    #pragma unroll
    for (int i = 0; i < 2; i++){
      int idx = i*512 + tid;
      int tt = idx >> 7, dd = idx & 127;
      float o = sO[0][tt][dd] + sO[1][tt][dd] + sO[2][tt][dd] + sO[3][tt][dd];
      obase[(size_t)(sb*TS_+tt)*1024 + dd] = f2bf(o);
    }
    __syncthreads();   // sO fully consumed before next sb overwrites it
  }
}

// ----------------------------- launch -----------------------------
extern "C" void kernel_launch(void* const* d_in, const int* in_sizes, int n_in,
                              void* d_out, int out_size, void* d_ws, size_t ws_size,
                              hipStream_t stream){
  const float* x     = (const float*)d_in[0];
  const float* Wq    = (const float*)d_in[1];
  const float* Wk    = (const float*)d_in[2];
  const float* Wv    = (const float*)d_in[3];
  const float* Qc    = (const float*)d_in[4];
  const float* Vc    = (const float*)d_in[5];
  const float* Wa_w  = (const float*)d_in[6];
  const float* Wa_b  = (const float*)d_in[7];
  const float* Wo    = (const float*)d_in[8];
  const float* gamma = (const float*)d_in[9];
  const float* beta  = (const float*)d_in[10];
  float* out = (float*)d_out;

  char* ws = (char*)d_ws;
  size_t off = 0;
  auto alloc = [&](size_t bytes) -> void* {
    void* p = ws + off; off += (bytes + 255) & ~(size_t)255; return p;
  };
  // total ws use: ~192.74 MB (round-1's 193.0 MB layout is proven to fit)
  // R1: xnb (bf16 M*1024) -> obuf (bf16 M*1024)
  char* R1 = (char*)alloc((size_t)M_ * 1024 * 2);
  u16*   xnb  = (u16*)R1;
  u16*   obuf = (u16*)R1;
  // R2: proj (f32 M*704) -> qf (f32 M*512)
  char* R2 = (char*)alloc((size_t)M_ * 704 * 4);
  float* proj = (float*)R2;
  float* qf   = (float*)R2;
  float* Sbuf   = (float*)alloc((size_t)64 * NC_ * 8192 * 4);   // 33.5 MB
  u16*   vfb    = (u16*)alloc((size_t)M_ * 1024 * 2);           // v bf16
  float* alphaf = (float*)alloc((size_t)M_ * 512 * 4);
  float* knf    = (float*)alloc((size_t)M_ * 64 * 4);
  u16*   qlatb  = (u16*)alloc((size_t)M_ * 64 * 2);
  u16*   vlatb  = (u16*)alloc((size_t)M_ * 64 * 2);
  u16*   Wcatb  = (u16*)alloc((size_t)704 * 1024 * 2);
  u16*   QcTb   = (u16*)alloc((size_t)512 * 64 * 2);
  u16*   VcTb   = (u16*)alloc((size_t)1024 * 64 * 2);
  u16*   Wob    = (u16*)alloc((size_t)1024 * 1024 * 2);
  float* btotp  = (float*)alloc((size_t)64 * NC_ * 64 * 4);
  (void)ws_size; (void)in_sizes; (void)n_in; (void)out_size;

  ln_kernel<<<dim3(M_), dim3(256), 0, stream>>>(x, gamma, beta, xnb);
  prep_weights<<<dim3(7296), dim3(256), 0, stream>>>(
      Wq, Wk, Wv, Wa_w, Qc, Vc, Wo, Wcatb, QcTb, VcTb, Wob);
  gemm_bf16<<<dim3(M_/128, 704/64), dim3(256), 0, stream>>>(
      xnb, Wcatb, proj, nullptr, nullptr, 704, 1024);
  split_proj<<<dim3(M_/4), dim3(256), 0, stream>>>(
      proj, Wa_b, qlatb, knf, vlatb, alphaf);
  // v = v_lat @ VcT^T : (M,1024) bf16 out
  gemm_bf16<<<dim3(M_/128, 1024/64), dim3(256), 0, stream>>>(
      vlatb, VcTb, nullptr, nullptr, vfb, 1024, 64);
  // q = q_lat @ QcT^T : (M,512) f32 into R2 (proj dead after split_proj)
  gemm_bf16<<<dim3(M_/128, 512/64), dim3(256), 0, stream>>>(
      qlatb, QcTb, qf, nullptr, nullptr, 512, 64);
  scan_pass1<<<dim3(NC_-1, 64), dim3(512), 0, stream>>>(
      knf, vfb, alphaf, Sbuf, btotp);
  scan_combine<<<dim3(64), dim3(256), 0, stream>>>(Sbuf, btotp);
  scan_pass2<<<dim3(NC_, 64), dim3(512), 0, stream>>>(
      qf, knf, vfb, alphaf, Sbuf, obuf);
  gemm_bf16<<<dim3(M_/128, 1024/64), dim3(256), 0, stream>>>(
      obuf, Wob, out, x, nullptr, 1024, 1024);
}

// Round 2
// 538.884 us; speedup vs baseline: 1.0535x; 1.0105x over previous
//
#include <hip/hip_runtime.h>

typedef unsigned short u16;
typedef unsigned int   u32;
typedef __bf16 bf16x8 __attribute__((ext_vector_type(8)));
typedef float  f32x4  __attribute__((ext_vector_type(4)));
typedef float  f32x8  __attribute__((ext_vector_type(8)));

#define B_  8
#define T_  2048
#define D_  1024
#define H_  8
#define C_  64
#define DV_ 128
#define M_  (B_*T_)   // 16384
#define L_  128       // scan chunk length
#define NC_ (T_/L_)   // 16 chunks

__device__ __forceinline__ u16 f2bf(float f){
  u32 u = __float_as_uint(f);
  u32 r = (u + 0x7fffu + ((u >> 16) & 1u)) >> 16;   // RNE
  return (u16)r;
}
__device__ __forceinline__ float bf2f(u16 u){
  return __uint_as_float(((u32)u) << 16);
}

// ---------------- LayerNorm: x (M,1024) f32 -> xn bf16 ----------------
__global__ __launch_bounds__(256) void ln_kernel(
    const float* __restrict__ x, const float* __restrict__ gamma,
    const float* __restrict__ beta, u16* __restrict__ xnb){
  const int m = blockIdx.x;
  const int tid = threadIdx.x;
  const int wave = tid >> 6, lane = tid & 63;
  const float* xr = x + (size_t)m * D_;
  float4 xv = *(const float4*)&xr[tid*4];
  float s = xv.x + xv.y + xv.z + xv.w;
  #pragma unroll
  for (int off = 32; off > 0; off >>= 1) s += __shfl_xor(s, off, 64);
  __shared__ float red[8];
  if (lane == 0) red[wave] = s;
  __syncthreads();
  float mu = (red[0]+red[1]+red[2]+red[3]) * (1.f/1024.f);
  float dx = xv.x-mu, dy = xv.y-mu, dz = xv.z-mu, dw = xv.w-mu;
  float ss = dx*dx + dy*dy + dz*dz + dw*dw;
  #pragma unroll
  for (int off = 32; off > 0; off >>= 1) ss += __shfl_xor(ss, off, 64);
  if (lane == 0) red[4+wave] = ss;
  __syncthreads();
  float var = (red[4]+red[5]+red[6]+red[7]) * (1.f/1024.f);
  float rs = rsqrtf(var + 1e-5f);
  float4 g  = *(const float4*)&gamma[tid*4];
  float4 bb = *(const float4*)&beta[tid*4];
  ushort4 o4;
  o4.x = f2bf(dx*rs*g.x + bb.x);
  o4.y = f2bf(dy*rs*g.y + bb.y);
  o4.z = f2bf(dz*rs*g.z + bb.z);
  o4.w = f2bf(dw*rs*g.w + bb.w);
  *(ushort4*)&xnb[(size_t)m*D_ + tid*4] = o4;
}

// ------------- weight prep: convert/concat/transpose to bf16 -------------
__global__ __launch_bounds__(256) void prep_weights(
    const float* __restrict__ Wq, const float* __restrict__ Wk,
    const float* __restrict__ Wv, const float* __restrict__ Wa,
    const float* __restrict__ Qc, const float* __restrict__ Vc,
    const float* __restrict__ Wo,
    u16* __restrict__ Wcatb, u16* __restrict__ QcTb,
    u16* __restrict__ VcTb,  u16* __restrict__ Wob){
  int idx = blockIdx.x * 256 + threadIdx.x;
  if (idx < 720896){                       // 704*1024
    int r = idx >> 10, col = idx & 1023;
    float v;
    if (r < 64)       v = Wq[(size_t)r*1024 + col];
    else if (r < 128) v = Wk[(size_t)(r-64)*1024 + col];
    else if (r < 192) v = Wv[(size_t)(r-128)*1024 + col];
    else              v = Wa[(size_t)(r-192)*1024 + col];
    Wcatb[idx] = f2bf(v);
  } else if (idx < 753664){                // +512*64
    int i = idx - 720896;
    int n = i >> 6, c = i & 63; int h = n >> 6, e = n & 63;
    QcTb[i] = f2bf(Qc[((size_t)h*64 + c)*64 + e]);
  } else if (idx < 819200){                // +1024*64
    int i = idx - 753664;
    int n = i >> 6, c = i & 63; int h = n >> 7, d = n & 127;
    VcTb[i] = f2bf(Vc[((size_t)h*64 + c)*128 + d]);
  } else if (idx < 1867776){               // +1024*1024
    int i = idx - 819200;
    Wob[i] = f2bf(Wo[i]);
  }
}

// ------------- generic bf16 MFMA GEMM: C = A[M,K] @ Bw[N,K]^T (+res) -------
__global__ __launch_bounds__(256) void gemm_bf16(
    const u16* __restrict__ A, const u16* __restrict__ Bw,
    float* __restrict__ C, const float* __restrict__ res,
    u16* __restrict__ Cb, int N, int K){
  __shared__ u16 As[128][36];
  __shared__ u16 Bs[64][36];
  const int tid = threadIdx.x;
  const int wave = tid >> 6;
  const int lane = tid & 63;
  const int q  = lane >> 4;
  const int mr = lane & 15;
  const int m0 = blockIdx.x * 128;
  const int n0 = blockIdx.y * 64;

  union FragU { u32 u[4]; bf16x8 v; };
  f32x4 zero = {0.f, 0.f, 0.f, 0.f};
  f32x4 acc[2][4];
  #pragma unroll
  for (int i = 0; i < 2; i++)
    #pragma unroll
    for (int j = 0; j < 4; j++) acc[i][j] = zero;

  for (int k0 = 0; k0 < K; k0 += 32){
    #pragma unroll
    for (int p = 0; p < 2; ++p){
      int ch = p*256 + tid;
      int r = ch >> 2, c4 = ch & 3;
      const uint4 val = *(const uint4*)(&A[(size_t)(m0 + r)*K + k0 + c4*8]);
      u32* dst = (u32*)&As[r][c4*8];
      dst[0]=val.x; dst[1]=val.y; dst[2]=val.z; dst[3]=val.w;
    }
    {
      int r = tid >> 2, c4 = tid & 3;
      const uint4 val = *(const uint4*)(&Bw[(size_t)(n0 + r)*K + k0 + c4*8]);
      u32* dst = (u32*)&Bs[r][c4*8];
      dst[0]=val.x; dst[1]=val.y; dst[2]=val.z; dst[3]=val.w;
    }
    __syncthreads();
    bf16x8 afr[2], bfr[4];
    #pragma unroll
    for (int mt = 0; mt < 2; mt++){
      const u32* p = (const u32*)&As[wave*32 + mt*16 + mr][q*8];
      FragU f; f.u[0]=p[0]; f.u[1]=p[1]; f.u[2]=p[2]; f.u[3]=p[3];
      afr[mt] = f.v;
    }
    #pragma unroll
    for (int nt = 0; nt < 4; nt++){
      const u32* p = (const u32*)&Bs[nt*16 + mr][q*8];
      FragU f; f.u[0]=p[0]; f.u[1]=p[1]; f.u[2]=p[2]; f.u[3]=p[3];
      bfr[nt] = f.v;
    }
    #pragma unroll
    for (int mt = 0; mt < 2; mt++)
      #pragma unroll
      for (int nt = 0; nt < 4; nt++)
        acc[mt][nt] = __builtin_amdgcn_mfma_f32_16x16x32_bf16(
            afr[mt], bfr[nt], acc[mt][nt], 0, 0, 0);
    __syncthreads();
  }

  #pragma unroll
  for (int mt = 0; mt < 2; mt++)
    #pragma unroll
    for (int nt = 0; nt < 4; nt++)
      #pragma unroll
      for (int r = 0; r < 4; r++){
        int row = m0 + wave*32 + mt*16 + q*4 + r;
        int col = n0 + nt*16 + mr;
        size_t idx = (size_t)row * N + col;
        float v = acc[mt][nt][r];
        if (res) v += res[idx];
        if (Cb) Cb[idx] = f2bf(v);
        else    C[idx] = v;
      }
}

// ------------- split proj (M x 704) -------------
__global__ __launch_bounds__(256) void split_proj(
    const float* __restrict__ proj, const float* __restrict__ Wab,
    u16* __restrict__ qlatb, float* __restrict__ knf,
    u16* __restrict__ vlatb, float* __restrict__ alphaf){
  const int m = blockIdx.x * 4 + (threadIdx.x >> 6);
  const int lane = threadIdx.x & 63;
  const float* pr = proj + (size_t)m * 704;
  qlatb[(size_t)m*64 + lane] = f2bf(pr[lane]);
  float kv = pr[64 + lane];
  float ss = kv * kv;
  #pragma unroll
  for (int off = 32; off > 0; off >>= 1) ss += __shfl_xor(ss, off, 64);
  float nrm = fmaxf(sqrtf(ss), 1e-12f);
  knf[(size_t)m*64 + lane] = kv / nrm;
  vlatb[(size_t)m*64 + lane] = f2bf(pr[128 + lane]);
  #pragma unroll
  for (int j = 0; j < 8; j++){
    int jj = j*64 + lane;
    float av = pr[192 + jj] + Wab[jj];
    alphaf[(size_t)m*512 + jj] = 1.f / (1.f + expf(-av));
  }
}

// ===================== blocked two-pass gated scan =====================
// Partition (round-2): 512 threads = 8 waves. wave w owns channel slice
// [8w, 8w+8); lane dg in [0,64) owns value columns {2dg, 2dg+1}. Each
// thread holds S[8][2].
//
// Round-1 lesson: s_load + per-tt lgkmcnt(0) serializes one ~600-900 cyc
// L2/L3-miss latency against only 112 cyc of compute -> VALUBusy 56%.
// SMEM returns are OUT-OF-ORDER, so counted lgkmcnt pipelining is unsafe;
// instead we amortize: the (8,2) split halves the broadcast bytes per tt,
// so a 2-timestep batch (a/k/q for 2 tt = 48 SGPRs) fits under the 102-SGPR
// budget behind ONE lgkmcnt(0). Compute per wait doubles, and with 8
// waves/SIMD (VGPR<64, LDS 32KB, grid=1024 blocks=4/CU) the stall is fully
// covered: 8 waves x ~220 cyc >> 900 cyc latency.

__global__ __launch_bounds__(512, 8) void scan_pass1(
    const float* __restrict__ knf, const u16* __restrict__ vb,
    const float* __restrict__ alphaf,
    float* __restrict__ Sbuf, float* __restrict__ btot){
  const int ch = blockIdx.x;        // 0..NC_-2 (last chunk's state unused)
  const int bh = blockIdx.y;
  const int b = bh >> 3, h = bh & 7;
  const int tid = threadIdx.x;
  const int w = __builtin_amdgcn_readfirstlane(tid >> 6);  // wave = ch-group
  const int dg = tid & 63;
  const int t0 = ch * L_;

  const float* kp  = knf    + ((size_t)(b*T_ + t0))*64  + w*8;
  const float* ap  = alphaf + ((size_t)(b*T_ + t0))*512 + h*64 + w*8;
  const float* alp = ap + (dg & 7);            // per-lane alpha for btot
  const u32*   vp  = (const u32*)(vb + ((size_t)(b*T_ + t0))*1024 + h*128) + dg;

  float S[8][2];
  #pragma unroll
  for (int j = 0; j < 8; j++){ S[j][0] = 0.f; S[j][1] = 0.f; }
  float bt = 1.f;

  for (int t = 0; t < L_; t += 2){
    f32x8 a0, a1, k0, k1;
    asm volatile(
      "s_load_dwordx8 %0, %4, 0x0\n\t"
      "s_load_dwordx8 %1, %4, 0x800\n\t"
      "s_load_dwordx8 %2, %5, 0x0\n\t"
      "s_load_dwordx8 %3, %5, 0x100\n\t"
      "s_waitcnt lgkmcnt(0)"
      : "=&s"(a0), "=&s"(a1), "=&s"(k0), "=&s"(k1)
      : "s"(ap), "s"(kp));
    float al0 = alp[0], al1 = alp[512];
    u32 vv0 = vp[0], vv1 = vp[512];
    float v00 = __uint_as_float(vv0 << 16);
    float v01 = __uint_as_float(vv0 & 0xffff0000u);
    float v10 = __uint_as_float(vv1 << 16);
    float v11 = __uint_as_float(vv1 & 0xffff0000u);
    #pragma unroll
    for (int j = 0; j < 8; j++){
      S[j][0] = a0[j]*S[j][0] + k0[j]*v00;
      S[j][1] = a0[j]*S[j][1] + k0[j]*v01;
    }
    bt *= al0;
    #pragma unroll
    for (int j = 0; j < 8; j++){
      S[j][0] = a1[j]*S[j][0] + k1[j]*v10;
      S[j][1] = a1[j]*S[j][1] + k1[j]*v11;
    }
    bt *= al1;
    ap += 1024; kp += 128; alp += 1024; vp += 1024;
  }

  float* Sl = Sbuf + ((size_t)bh*NC_ + ch) * (64*128);
  #pragma unroll
  for (int j = 0; j < 8; j++)
    *(float2*)&Sl[(size_t)(w*8+j)*128 + 2*dg] = make_float2(S[j][0], S[j][1]);
  if (dg < 8) btot[((size_t)bh*NC_ + ch)*64 + w*8 + dg] = bt;
}

// in-place: Sbuf[ch] (local states) -> Sbuf[ch] (prefix init states)
__global__ __launch_bounds__(256) void scan_combine(
    float* __restrict__ Sbuf, const float* __restrict__ btot){
  const int bh = blockIdx.x;
  const int tid = threadIdx.x;
  float S[32];
  #pragma unroll
  for (int i = 0; i < 32; i++) S[i] = 0.f;
  float*       Sb  = Sbuf + (size_t)bh*NC_*8192;
  const float* btb = btot + (size_t)bh*NC_*64;
  for (int j = 0; j < NC_; j++){
    if (j < NC_-1){
      #pragma unroll
      for (int i = 0; i < 32; i++){
        int e = i*256 + tid;
        float loc = Sb[(size_t)j*8192 + e];          // read local BEFORE overwrite
        float bv  = btb[j*64 + (e >> 7)];
        Sb[(size_t)j*8192 + e] = S[i];               // write prefix state
        S[i] = bv * S[i] + loc;
      }
    } else {
      #pragma unroll
      for (int i = 0; i < 32; i++) Sb[(size_t)j*8192 + i*256 + tid] = S[i];
    }
  }
}

__global__ __launch_bounds__(512, 8) void scan_pass2(
    const float* __restrict__ qf, const float* __restrict__ knf,
    const u16* __restrict__ vb, const float* __restrict__ alphaf,
    const float* __restrict__ Sbuf, u16* __restrict__ ob){
  const int ch = blockIdx.x;        // 0..NC_-1
  const int bh = blockIdx.y;
  const int b = bh >> 3, h = bh & 7;
  const int tid = threadIdx.x;
  const int w = __builtin_amdgcn_readfirstlane(tid >> 6);  // wave = ch-group
  const int dg = tid & 63;
  const int t0 = ch * L_;
  __shared__ __align__(16) float sO[2][8][4][128];   // 32 KB, double-buffered

  const float* qp = qf     + ((size_t)(b*T_ + t0))*512 + h*64 + w*8;
  const float* kp = knf    + ((size_t)(b*T_ + t0))*64  + w*8;
  const float* ap = alphaf + ((size_t)(b*T_ + t0))*512 + h*64 + w*8;
  const u32*   vp = (const u32*)(vb + ((size_t)(b*T_ + t0))*1024 + h*128) + dg;
  u16* obase = ob + ((size_t)(b*T_ + t0))*1024 + h*128;

  float S[8][2];
  const float* Si = Sbuf + ((size_t)bh*NC_ + ch) * (64*128);
  #pragma unroll
  for (int j = 0; j < 8; j++){
    float2 s2 = *(const float2*)&Si[(size_t)(w*8+j)*128 + 2*dg];
    S[j][0] = s2.x; S[j][1] = s2.y;
  }

  const int rtt = tid >> 7, rdd = tid & 127;   // reduction mapping (4tt x 128d)

  for (int sb = 0; sb < L_/4; sb++){
    const int p = sb & 1;
    #pragma unroll
    for (int half = 0; half < 2; half++){
      f32x8 a0, a1, k0, k1, q0, q1;
      asm volatile(
        "s_load_dwordx8 %0, %6, 0x0\n\t"
        "s_load_dwordx8 %1, %6, 0x800\n\t"
        "s_load_dwordx8 %2, %7, 0x0\n\t"
        "s_load_dwordx8 %3, %7, 0x100\n\t"
        "s_load_dwordx8 %4, %8, 0x0\n\t"
        "s_load_dwordx8 %5, %8, 0x800\n\t"
        "s_waitcnt lgkmcnt(0)"
        : "=&s"(a0), "=&s"(a1), "=&s"(k0), "=&s"(k1), "=&s"(q0), "=&s"(q1)
        : "s"(ap), "s"(kp), "s"(qp));
      u32 vv0 = vp[0], vv1 = vp[512];
      float v00 = __uint_as_float(vv0 << 16);
      float v01 = __uint_as_float(vv0 & 0xffff0000u);
      float v10 = __uint_as_float(vv1 << 16);
      float v11 = __uint_as_float(vv1 & 0xffff0000u);
      // ---- tt0 of pair ----
      {
        float oa0, oa1, ob0, ob1;          // 2 accum chains per column
        S[0][0] = a0[0]*S[0][0] + k0[0]*v00;  oa0 = S[0][0]*q0[0];
        S[0][1] = a0[0]*S[0][1] + k0[0]*v01;  oa1 = S[0][1]*q0[0];
        S[1][0] = a0[1]*S[1][0] + k0[1]*v00;  ob0 = S[1][0]*q0[1];
        S[1][1] = a0[1]*S[1][1] + k0[1]*v01;  ob1 = S[1][1]*q0[1];
        #pragma unroll
        for (int j = 2; j < 8; j += 2){
          S[j][0]   = a0[j]*S[j][0]     + k0[j]*v00;    oa0 += S[j][0]*q0[j];
          S[j][1]   = a0[j]*S[j][1]     + k0[j]*v01;    oa1 += S[j][1]*q0[j];
          S[j+1][0] = a0[j+1]*S[j+1][0] + k0[j+1]*v00;  ob0 += S[j+1][0]*q0[j+1];
          S[j+1][1] = a0[j+1]*S[j+1][1] + k0[j+1]*v01;  ob1 += S[j+1][1]*q0[j+1];
        }
        *(float2*)&sO[p][w][half*2+0][2*dg] = make_float2(oa0+ob0, oa1+ob1);
      }
      // ---- tt1 of pair ----
      {
        float oa0, oa1, ob0, ob1;
        S[0][0] = a1[0]*S[0][0] + k1[0]*v10;  oa0 = S[0][0]*q1[0];
        S[0][1] = a1[0]*S[0][1] + k1[0]*v11;  oa1 = S[0][1]*q1[0];
        S[1][0] = a1[1]*S[1][0] + k1[1]*v10;  ob0 = S[1][0]*q1[1];
        S[1][1] = a1[1]*S[1][1] + k1[1]*v11;  ob1 = S[1][1]*q1[1];
        #pragma unroll
        for (int j = 2; j < 8; j += 2){
          S[j][0]   = a1[j]*S[j][0]     + k1[j]*v10;    oa0 += S[j][0]*q1[j];
          S[j][1]   = a1[j]*S[j][1]     + k1[j]*v11;    oa1 += S[j][1]*q1[j];
          S[j+1][0] = a1[j+1]*S[j+1][0] + k1[j+1]*v10;  ob0 += S[j+1][0]*q1[j+1];
          S[j+1][1] = a1[j+1]*S[j+1][1] + k1[j+1]*v11;  ob1 += S[j+1][1]*q1[j+1];
        }
        *(float2*)&sO[p][w][half*2+1][2*dg] = make_float2(oa0+ob0, oa1+ob1);
      }
      ap += 1024; kp += 128; qp += 1024; vp += 1024;
    }
    __syncthreads();
    // reduce 8 wave-partials; double-buffered sO -> next sb writes hit p^1,
    // so no second barrier is needed (next write to THIS buffer is gated by
    // the following __syncthreads()).
    float o = sO[p][0][rtt][rdd] + sO[p][1][rtt][rdd]
            + sO[p][2][rtt][rdd] + sO[p][3][rtt][rdd]
            + sO[p][4][rtt][rdd] + sO[p][5][rtt][rdd]
            + sO[p][6][rtt][rdd] + sO[p][7][rtt][rdd];
    obase[(size_t)(sb*4 + rtt)*1024 + rdd] = f2bf(o);
  }
}

// ----------------------------- launch -----------------------------
extern "C" void kernel_launch(void* const* d_in, const int* in_sizes, int n_in,
                              void* d_out, int out_size, void* d_ws, size_t ws_size,
                              hipStream_t stream){
  const float* x     = (const float*)d_in[0];
  const float* Wq    = (const float*)d_in[1];
  const float* Wk    = (const float*)d_in[2];
  const float* Wv    = (const float*)d_in[3];
  const float* Qc    = (const float*)d_in[4];
  const float* Vc    = (const float*)d_in[5];
  const float* Wa_w  = (const float*)d_in[6];
  const float* Wa_b  = (const float*)d_in[7];
  const float* Wo    = (const float*)d_in[8];
  const float* gamma = (const float*)d_in[9];
  const float* beta  = (const float*)d_in[10];
  float* out = (float*)d_out;

  char* ws = (char*)d_ws;
  size_t off = 0;
  auto alloc = [&](size_t bytes) -> void* {
    void* p = ws + off; off += (bytes + 255) & ~(size_t)255; return p;
  };
  // total ws use: ~192.74 MB (round-1's 193.0 MB layout is proven to fit)
  // R1: xnb (bf16 M*1024) -> obuf (bf16 M*1024)
  char* R1 = (char*)alloc((size_t)M_ * 1024 * 2);
  u16*   xnb  = (u16*)R1;
  u16*   obuf = (u16*)R1;
  // R2: proj (f32 M*704) -> qf (f32 M*512)
  char* R2 = (char*)alloc((size_t)M_ * 704 * 4);
  float* proj = (float*)R2;
  float* qf   = (float*)R2;
  float* Sbuf   = (float*)alloc((size_t)64 * NC_ * 8192 * 4);   // 33.5 MB
  u16*   vfb    = (u16*)alloc((size_t)M_ * 1024 * 2);           // v bf16
  float* alphaf = (float*)alloc((size_t)M_ * 512 * 4);
  float* knf    = (float*)alloc((size_t)M_ * 64 * 4);
  u16*   qlatb  = (u16*)alloc((size_t)M_ * 64 * 2);
  u16*   vlatb  = (u16*)alloc((size_t)M_ * 64 * 2);
  u16*   Wcatb  = (u16*)alloc((size_t)704 * 1024 * 2);
  u16*   QcTb   = (u16*)alloc((size_t)512 * 64 * 2);
  u16*   VcTb   = (u16*)alloc((size_t)1024 * 64 * 2);
  u16*   Wob    = (u16*)alloc((size_t)1024 * 1024 * 2);
  float* btotp  = (float*)alloc((size_t)64 * NC_ * 64 * 4);
  (void)ws_size; (void)in_sizes; (void)n_in; (void)out_size;

  ln_kernel<<<dim3(M_), dim3(256), 0, stream>>>(x, gamma, beta, xnb);
  prep_weights<<<dim3(7296), dim3(256), 0, stream>>>(
      Wq, Wk, Wv, Wa_w, Qc, Vc, Wo, Wcatb, QcTb, VcTb, Wob);
  gemm_bf16<<<dim3(M_/128, 704/64), dim3(256), 0, stream>>>(
      xnb, Wcatb, proj, nullptr, nullptr, 704, 1024);
  split_proj<<<dim3(M_/4), dim3(256), 0, stream>>>(
      proj, Wa_b, qlatb, knf, vlatb, alphaf);
  // v = v_lat @ VcT^T : (M,1024) bf16 out
  gemm_bf16<<<dim3(M_/128, 1024/64), dim3(256), 0, stream>>>(
      vlatb, VcTb, nullptr, nullptr, vfb, 1024, 64);
  // q = q_lat @ QcT^T : (M,512) f32 into R2 (proj dead after split_proj)
  gemm_bf16<<<dim3(M_/128, 512/64), dim3(256), 0, stream>>>(
      qlatb, QcTb, qf, nullptr, nullptr, 512, 64);
  scan_pass1<<<dim3(NC_-1, 64), dim3(512), 0, stream>>>(
      knf, vfb, alphaf, Sbuf, btotp);
  scan_combine<<<dim3(64), dim3(256), 0, stream>>>(Sbuf, btotp);
  scan_pass2<<<dim3(NC_, 64), dim3(512), 0, stream>>>(
      qf, knf, vfb, alphaf, Sbuf, obuf);
  gemm_bf16<<<dim3(M_/128, 1024/64), dim3(256), 0, stream>>>(
      obuf, Wob, out, x, nullptr, 1024, 1024);
}

// Round 3
// 520.576 us; speedup vs baseline: 1.0906x; 1.0352x over previous
//
#include <hip/hip_runtime.h>

typedef unsigned short u16;
typedef unsigned int   u32;
typedef __bf16 bf16x8 __attribute__((ext_vector_type(8)));
typedef float  f32x4  __attribute__((ext_vector_type(4)));
typedef float  f32x8  __attribute__((ext_vector_type(8)));

#define B_  8
#define T_  2048
#define D_  1024
#define H_  8
#define C_  64
#define DV_ 128
#define M_  (B_*T_)   // 16384
#define L_  128       // scan chunk length
#define NC_ (T_/L_)   // 16 chunks

__device__ __forceinline__ u16 f2bf(float f){
  u32 u = __float_as_uint(f);
  u32 r = (u + 0x7fffu + ((u >> 16) & 1u)) >> 16;   // RNE
  return (u16)r;
}
__device__ __forceinline__ float bf2f(u16 u){
  return __uint_as_float(((u32)u) << 16);
}

// async global->LDS, 16B per lane; LDS dest is wave-uniform base + lane*16
typedef const __attribute__((address_space(1))) unsigned int* gp1_t;
typedef __attribute__((address_space(3))) unsigned int* lp3_t;
__device__ __forceinline__ void stage16(const void* g, void* l){
  __builtin_amdgcn_global_load_lds((gp1_t)g, (lp3_t)l, 16, 0, 0);
}

// ---------------- LayerNorm: x (M,1024) f32 -> xn bf16 ----------------
__global__ __launch_bounds__(256) void ln_kernel(
    const float* __restrict__ x, const float* __restrict__ gamma,
    const float* __restrict__ beta, u16* __restrict__ xnb){
  const int m = blockIdx.x;
  const int tid = threadIdx.x;
  const int wave = tid >> 6, lane = tid & 63;
  const float* xr = x + (size_t)m * D_;
  float4 xv = *(const float4*)&xr[tid*4];
  float s = xv.x + xv.y + xv.z + xv.w;
  #pragma unroll
  for (int off = 32; off > 0; off >>= 1) s += __shfl_xor(s, off, 64);
  __shared__ float red[8];
  if (lane == 0) red[wave] = s;
  __syncthreads();
  float mu = (red[0]+red[1]+red[2]+red[3]) * (1.f/1024.f);
  float dx = xv.x-mu, dy = xv.y-mu, dz = xv.z-mu, dw = xv.w-mu;
  float ss = dx*dx + dy*dy + dz*dz + dw*dw;
  #pragma unroll
  for (int off = 32; off > 0; off >>= 1) ss += __shfl_xor(ss, off, 64);
  if (lane == 0) red[4+wave] = ss;
  __syncthreads();
  float var = (red[4]+red[5]+red[6]+red[7]) * (1.f/1024.f);
  float rs = rsqrtf(var + 1e-5f);
  float4 g  = *(const float4*)&gamma[tid*4];
  float4 bb = *(const float4*)&beta[tid*4];
  ushort4 o4;
  o4.x = f2bf(dx*rs*g.x + bb.x);
  o4.y = f2bf(dy*rs*g.y + bb.y);
  o4.z = f2bf(dz*rs*g.z + bb.z);
  o4.w = f2bf(dw*rs*g.w + bb.w);
  *(ushort4*)&xnb[(size_t)m*D_ + tid*4] = o4;
}

// ------------- weight prep: convert/concat/transpose to bf16 -------------
// Wcat is padded to 768 rows (zeros in 704..767) so the 128-wide GEMM B-tiles
// never read OOB.
__global__ __launch_bounds__(256) void prep_weights(
    const float* __restrict__ Wq, const float* __restrict__ Wk,
    const float* __restrict__ Wv, const float* __restrict__ Wa,
    const float* __restrict__ Qc, const float* __restrict__ Vc,
    const float* __restrict__ Wo,
    u16* __restrict__ Wcatb, u16* __restrict__ QcTb,
    u16* __restrict__ VcTb,  u16* __restrict__ Wob){
  int idx = blockIdx.x * 256 + threadIdx.x;
  if (idx < 786432){                       // 768*1024 (padded)
    int r = idx >> 10, col = idx & 1023;
    float v = 0.f;
    if (r < 64)       v = Wq[(size_t)r*1024 + col];
    else if (r < 128) v = Wk[(size_t)(r-64)*1024 + col];
    else if (r < 192) v = Wv[(size_t)(r-128)*1024 + col];
    else if (r < 704) v = Wa[(size_t)(r-192)*1024 + col];
    Wcatb[idx] = f2bf(v);
  } else if (idx < 819200){                // +512*64
    int i = idx - 786432;
    int n = i >> 6, c = i & 63; int h = n >> 6, e = n & 63;
    QcTb[i] = f2bf(Qc[((size_t)h*64 + c)*64 + e]);
  } else if (idx < 884736){                // +1024*64
    int i = idx - 819200;
    int n = i >> 6, c = i & 63; int h = n >> 7, d = n & 127;
    VcTb[i] = f2bf(Vc[((size_t)h*64 + c)*128 + d]);
  } else {                                 // +1024*1024 (grid = exact bound)
    int i = idx - 884736;
    Wob[i] = f2bf(Wo[i]);
  }
}

// ---- m97-style bf16 MFMA GEMM: C[M,N] = A[M,K] @ Bw[Nr,K]^T (+res) ----
// 128x128 tile, 4 waves (2x2), each wave 64x64 = 4x4 fragments, BK=32.
// Staging via global_load_lds width-16 into LINEAR LDS [128][32] (no pad:
// gload_lds writes base+lane*16). Caller guarantees Bw has ceil(N/128)*128
// valid rows; epilogue guards col<N.
__global__ __launch_bounds__(256) void gemm_bf16(
    const u16* __restrict__ A, const u16* __restrict__ Bw,
    float* __restrict__ C, const float* __restrict__ res,
    u16* __restrict__ Cb, int N, int K){
  __shared__ u16 As[128*32];
  __shared__ u16 Bs[128*32];
  const int tid = threadIdx.x;
  const int wave = tid >> 6;
  const int lane = tid & 63;
  const int q  = lane >> 4;
  const int mr = lane & 15;
  const int wr = wave >> 1, wc = wave & 1;
  const int m0 = blockIdx.x * 128;
  const int n0 = blockIdx.y * 128;

  // staging: 8 insts of 16 rows each for A and for B; wave issues insts
  // {2w, 2w+1} of each. lane covers row j*16 + (lane>>2), bytes (lane&3)*16.
  const int j0 = wave*2;
  const int lr = lane >> 2;
  const int lc = (lane & 3) * 8;
  const u16* pa0 = A  + (size_t)(m0 + (j0  )*16 + lr)*K + lc;
  const u16* pa1 = A  + (size_t)(m0 + (j0+1)*16 + lr)*K + lc;
  const u16* pb0 = Bw + (size_t)(n0 + (j0  )*16 + lr)*K + lc;
  const u16* pb1 = Bw + (size_t)(n0 + (j0+1)*16 + lr)*K + lc;
  u16* la0 = &As[(j0  )*512];
  u16* la1 = &As[(j0+1)*512];
  u16* lb0 = &Bs[(j0  )*512];
  u16* lb1 = &Bs[(j0+1)*512];

  union FragU { uint4 u4; bf16x8 v; };
  f32x4 zero = {0.f, 0.f, 0.f, 0.f};
  f32x4 acc[4][4];
  #pragma unroll
  for (int i = 0; i < 4; i++)
    #pragma unroll
    for (int j = 0; j < 4; j++) acc[i][j] = zero;

  const u16* fA = &As[(size_t)(wr*64 + mr)*32 + q*8];
  const u16* fB = &Bs[(size_t)(wc*64 + mr)*32 + q*8];

  for (int k0 = 0; k0 < K; k0 += 32){
    stage16(pa0, la0);
    stage16(pa1, la1);
    stage16(pb0, lb0);
    stage16(pb1, lb1);
    pa0 += 32; pa1 += 32; pb0 += 32; pb1 += 32;
    __syncthreads();           // drains vmcnt(0): tile resident for all waves
    bf16x8 afr[4], bfr[4];
    #pragma unroll
    for (int mt = 0; mt < 4; mt++){
      FragU f; f.u4 = *(const uint4*)(fA + mt*512);   // 16 rows * 32
      afr[mt] = f.v;
    }
    #pragma unroll
    for (int nt = 0; nt < 4; nt++){
      FragU f; f.u4 = *(const uint4*)(fB + nt*512);
      bfr[nt] = f.v;
    }
    #pragma unroll
    for (int mt = 0; mt < 4; mt++)
      #pragma unroll
      for (int nt = 0; nt < 4; nt++)
        acc[mt][nt] = __builtin_amdgcn_mfma_f32_16x16x32_bf16(
            afr[mt], bfr[nt], acc[mt][nt], 0, 0, 0);
    __syncthreads();           // all waves done reading before next overwrite
  }

  #pragma unroll
  for (int mt = 0; mt < 4; mt++)
    #pragma unroll
    for (int nt = 0; nt < 4; nt++){
      int col = n0 + wc*64 + nt*16 + mr;
      if (col < N){
        #pragma unroll
        for (int r = 0; r < 4; r++){
          int row = m0 + wr*64 + mt*16 + q*4 + r;
          size_t idx = (size_t)row * N + col;
          float v = acc[mt][nt][r];
          if (res) v += res[idx];
          if (Cb) Cb[idx] = f2bf(v);
          else    C[idx] = v;
        }
      }
    }
}

// ------------- split proj (M x 704) -------------
__global__ __launch_bounds__(256) void split_proj(
    const float* __restrict__ proj, const float* __restrict__ Wab,
    u16* __restrict__ qlatb, float* __restrict__ knf,
    u16* __restrict__ vlatb, float* __restrict__ alphaf){
  const int m = blockIdx.x * 4 + (threadIdx.x >> 6);
  const int lane = threadIdx.x & 63;
  const float* pr = proj + (size_t)m * 704;
  qlatb[(size_t)m*64 + lane] = f2bf(pr[lane]);
  float kv = pr[64 + lane];
  float ss = kv * kv;
  #pragma unroll
  for (int off = 32; off > 0; off >>= 1) ss += __shfl_xor(ss, off, 64);
  float nrm = fmaxf(sqrtf(ss), 1e-12f);
  knf[(size_t)m*64 + lane] = kv / nrm;
  vlatb[(size_t)m*64 + lane] = f2bf(pr[128 + lane]);
  #pragma unroll
  for (int j = 0; j < 8; j++){
    int jj = j*64 + lane;
    float av = pr[192 + jj] + Wab[jj];
    alphaf[(size_t)m*512 + jj] = 1.f / (1.f + expf(-av));
  }
}

// ===================== blocked two-pass gated scan =====================
// 512 threads = 8 waves. wave w owns channel slice [8w, 8w+8); lane dg owns
// value columns {2dg, 2dg+1}. a/k/q are wave-uniform -> SGPRs via
// s_load_dwordx8 (2 timesteps per lgkmcnt(0) to amortize SMEM latency).

__global__ __launch_bounds__(512, 8) void scan_pass1(
    const float* __restrict__ knf, const u16* __restrict__ vb,
    const float* __restrict__ alphaf,
    float* __restrict__ Sbuf, float* __restrict__ btot){
  const int ch = blockIdx.x;        // 0..NC_-2 (last chunk's state unused)
  const int bh = blockIdx.y;
  const int b = bh >> 3, h = bh & 7;
  const int tid = threadIdx.x;
  const int w = __builtin_amdgcn_readfirstlane(tid >> 6);  // wave = ch-group
  const int dg = tid & 63;
  const int t0 = ch * L_;

  const float* kp  = knf    + ((size_t)(b*T_ + t0))*64  + w*8;
  const float* ap  = alphaf + ((size_t)(b*T_ + t0))*512 + h*64 + w*8;
  const float* alp = ap + (dg & 7);            // per-lane alpha for btot
  const u32*   vp  = (const u32*)(vb + ((size_t)(b*T_ + t0))*1024 + h*128) + dg;

  float S[8][2];
  #pragma unroll
  for (int j = 0; j < 8; j++){ S[j][0] = 0.f; S[j][1] = 0.f; }
  float bt = 1.f;

  for (int t = 0; t < L_; t += 2){
    f32x8 a0, a1, k0, k1;
    asm volatile(
      "s_load_dwordx8 %0, %4, 0x0\n\t"
      "s_load_dwordx8 %1, %4, 0x800\n\t"
      "s_load_dwordx8 %2, %5, 0x0\n\t"
      "s_load_dwordx8 %3, %5, 0x100\n\t"
      "s_waitcnt lgkmcnt(0)"
      : "=&s"(a0), "=&s"(a1), "=&s"(k0), "=&s"(k1)
      : "s"(ap), "s"(kp));
    float al0 = alp[0], al1 = alp[512];
    u32 vv0 = vp[0], vv1 = vp[512];
    float v00 = __uint_as_float(vv0 << 16);
    float v01 = __uint_as_float(vv0 & 0xffff0000u);
    float v10 = __uint_as_float(vv1 << 16);
    float v11 = __uint_as_float(vv1 & 0xffff0000u);
    #pragma unroll
    for (int j = 0; j < 8; j++){
      S[j][0] = a0[j]*S[j][0] + k0[j]*v00;
      S[j][1] = a0[j]*S[j][1] + k0[j]*v01;
    }
    bt *= al0;
    #pragma unroll
    for (int j = 0; j < 8; j++){
      S[j][0] = a1[j]*S[j][0] + k1[j]*v10;
      S[j][1] = a1[j]*S[j][1] + k1[j]*v11;
    }
    bt *= al1;
    ap += 1024; kp += 128; alp += 1024; vp += 1024;
  }

  float* Sl = Sbuf + ((size_t)bh*NC_ + ch) * (64*128);
  #pragma unroll
  for (int j = 0; j < 8; j++)
    *(float2*)&Sl[(size_t)(w*8+j)*128 + 2*dg] = make_float2(S[j][0], S[j][1]);
  if (dg < 8) btot[((size_t)bh*NC_ + ch)*64 + w*8 + dg] = bt;
}

// in-place: Sbuf[ch] (local states) -> Sbuf[ch] (prefix init states)
// element-parallel: grid (32, 64), one element per thread, serial over chunks
__global__ __launch_bounds__(256) void scan_combine(
    float* __restrict__ Sbuf, const float* __restrict__ btot){
  const int bh = blockIdx.y;
  const int e  = blockIdx.x * 256 + threadIdx.x;   // 0..8191
  float*       Sb  = Sbuf + (size_t)bh*NC_*8192 + e;
  const float* btb = btot + (size_t)bh*NC_*64 + (e >> 7);
  float S = 0.f;
  #pragma unroll
  for (int j = 0; j < NC_; j++){
    float loc = Sb[(size_t)j*8192];
    Sb[(size_t)j*8192] = S;
    if (j < NC_-1) S = btb[j*64] * S + loc;
  }
}

__global__ __launch_bounds__(512, 8) void scan_pass2(
    const float* __restrict__ qf, const float* __restrict__ knf,
    const u16* __restrict__ vb, const float* __restrict__ alphaf,
    const float* __restrict__ Sbuf, u16* __restrict__ ob){
  const int ch = blockIdx.x;        // 0..NC_-1
  const int bh = blockIdx.y;
  const int b = bh >> 3, h = bh & 7;
  const int tid = threadIdx.x;
  const int w = __builtin_amdgcn_readfirstlane(tid >> 6);  // wave = ch-group
  const int dg = tid & 63;
  const int t0 = ch * L_;
  __shared__ __align__(16) float sO[2][8][4][128];   // 32 KB, double-buffered

  const float* qp = qf     + ((size_t)(b*T_ + t0))*512 + h*64 + w*8;
  const float* kp = knf    + ((size_t)(b*T_ + t0))*64  + w*8;
  const float* ap = alphaf + ((size_t)(b*T_ + t0))*512 + h*64 + w*8;
  const u32*   vp = (const u32*)(vb + ((size_t)(b*T_ + t0))*1024 + h*128) + dg;
  u16* obase = ob + ((size_t)(b*T_ + t0))*1024 + h*128;

  float S[8][2];
  const float* Si = Sbuf + ((size_t)bh*NC_ + ch) * (64*128);
  #pragma unroll
  for (int j = 0; j < 8; j++){
    float2 s2 = *(const float2*)&Si[(size_t)(w*8+j)*128 + 2*dg];
    S[j][0] = s2.x; S[j][1] = s2.y;
  }

  const int rtt = tid >> 7, rdd = tid & 127;   // reduction mapping (4tt x 128d)

  for (int sb = 0; sb < L_/4; sb++){
    const int p = sb & 1;
    #pragma unroll
    for (int half = 0; half < 2; half++){
      f32x8 a0, a1, k0, k1, q0, q1;
      asm volatile(
        "s_load_dwordx8 %0, %6, 0x0\n\t"
        "s_load_dwordx8 %1, %6, 0x800\n\t"
        "s_load_dwordx8 %2, %7, 0x0\n\t"
        "s_load_dwordx8 %3, %7, 0x100\n\t"
        "s_load_dwordx8 %4, %8, 0x0\n\t"
        "s_load_dwordx8 %5, %8, 0x800\n\t"
        "s_waitcnt lgkmcnt(0)"
        : "=&s"(a0), "=&s"(a1), "=&s"(k0), "=&s"(k1), "=&s"(q0), "=&s"(q1)
        : "s"(ap), "s"(kp), "s"(qp));
      u32 vv0 = vp[0], vv1 = vp[512];
      float v00 = __uint_as_float(vv0 << 16);
      float v01 = __uint_as_float(vv0 & 0xffff0000u);
      float v10 = __uint_as_float(vv1 << 16);
      float v11 = __uint_as_float(vv1 & 0xffff0000u);
      // ---- tt0 of pair ----
      {
        float oa0, oa1, ob0, ob1;          // 2 accum chains per column
        S[0][0] = a0[0]*S[0][0] + k0[0]*v00;  oa0 = S[0][0]*q0[0];
        S[0][1] = a0[0]*S[0][1] + k0[0]*v01;  oa1 = S[0][1]*q0[0];
        S[1][0] = a0[1]*S[1][0] + k0[1]*v00;  ob0 = S[1][0]*q0[1];
        S[1][1] = a0[1]*S[1][1] + k0[1]*v01;  ob1 = S[1][1]*q0[1];
        #pragma unroll
        for (int j = 2; j < 8; j += 2){
          S[j][0]   = a0[j]*S[j][0]     + k0[j]*v00;    oa0 += S[j][0]*q0[j];
          S[j][1]   = a0[j]*S[j][1]     + k0[j]*v01;    oa1 += S[j][1]*q0[j];
          S[j+1][0] = a0[j+1]*S[j+1][0] + k0[j+1]*v00;  ob0 += S[j+1][0]*q0[j+1];
          S[j+1][1] = a0[j+1]*S[j+1][1] + k0[j+1]*v01;  ob1 += S[j+1][1]*q0[j+1];
        }
        *(float2*)&sO[p][w][half*2+0][2*dg] = make_float2(oa0+ob0, oa1+ob1);
      }
      // ---- tt1 of pair ----
      {
        float oa0, oa1, ob0, ob1;
        S[0][0] = a1[0]*S[0][0] + k1[0]*v10;  oa0 = S[0][0]*q1[0];
        S[0][1] = a1[0]*S[0][1] + k1[0]*v11;  oa1 = S[0][1]*q1[0];
        S[1][0] = a1[1]*S[1][0] + k1[1]*v10;  ob0 = S[1][0]*q1[1];
        S[1][1] = a1[1]*S[1][1] + k1[1]*v11;  ob1 = S[1][1]*q1[1];
        #pragma unroll
        for (int j = 2; j < 8; j += 2){
          S[j][0]   = a1[j]*S[j][0]     + k1[j]*v10;    oa0 += S[j][0]*q1[j];
          S[j][1]   = a1[j]*S[j][1]     + k1[j]*v11;    oa1 += S[j][1]*q1[j];
          S[j+1][0] = a1[j+1]*S[j+1][0] + k1[j+1]*v10;  ob0 += S[j+1][0]*q1[j+1];
          S[j+1][1] = a1[j+1]*S[j+1][1] + k1[j+1]*v11;  ob1 += S[j+1][1]*q1[j+1];
        }
        *(float2*)&sO[p][w][half*2+1][2*dg] = make_float2(oa0+ob0, oa1+ob1);
      }
      ap += 1024; kp += 128; qp += 1024; vp += 1024;
    }
    __syncthreads();
    // reduce 8 wave-partials; double-buffered sO -> next sb writes hit p^1,
    // so no second barrier is needed.
    float o = sO[p][0][rtt][rdd] + sO[p][1][rtt][rdd]
            + sO[p][2][rtt][rdd] + sO[p][3][rtt][rdd]
            + sO[p][4][rtt][rdd] + sO[p][5][rtt][rdd]
            + sO[p][6][rtt][rdd] + sO[p][7][rtt][rdd];
    obase[(size_t)(sb*4 + rtt)*1024 + rdd] = f2bf(o);
  }
}

// ----------------------------- launch -----------------------------
extern "C" void kernel_launch(void* const* d_in, const int* in_sizes, int n_in,
                              void* d_out, int out_size, void* d_ws, size_t ws_size,
                              hipStream_t stream){
  const float* x     = (const float*)d_in[0];
  const float* Wq    = (const float*)d_in[1];
  const float* Wk    = (const float*)d_in[2];
  const float* Wv    = (const float*)d_in[3];
  const float* Qc    = (const float*)d_in[4];
  const float* Vc    = (const float*)d_in[5];
  const float* Wa_w  = (const float*)d_in[6];
  const float* Wa_b  = (const float*)d_in[7];
  const float* Wo    = (const float*)d_in[8];
  const float* gamma = (const float*)d_in[9];
  const float* beta  = (const float*)d_in[10];
  float* out = (float*)d_out;

  char* ws = (char*)d_ws;
  size_t off = 0;
  auto alloc = [&](size_t bytes) -> void* {
    void* p = ws + off; off += (bytes + 255) & ~(size_t)255; return p;
  };
  // R1: xnb (bf16 M*1024) -> obuf (bf16 M*1024)
  char* R1 = (char*)alloc((size_t)M_ * 1024 * 2);
  u16*   xnb  = (u16*)R1;
  u16*   obuf = (u16*)R1;
  // R2: proj (f32 M*704) -> qf (f32 M*512)
  char* R2 = (char*)alloc((size_t)M_ * 704 * 4);
  float* proj = (float*)R2;
  float* qf   = (float*)R2;
  float* Sbuf   = (float*)alloc((size_t)64 * NC_ * 8192 * 4);   // 33.5 MB
  u16*   vfb    = (u16*)alloc((size_t)M_ * 1024 * 2);           // v bf16
  float* alphaf = (float*)alloc((size_t)M_ * 512 * 4);
  float* knf    = (float*)alloc((size_t)M_ * 64 * 4);
  u16*   qlatb  = (u16*)alloc((size_t)M_ * 64 * 2);
  u16*   vlatb  = (u16*)alloc((size_t)M_ * 64 * 2);
  u16*   Wcatb  = (u16*)alloc((size_t)768 * 1024 * 2);          // padded to 768
  u16*   QcTb   = (u16*)alloc((size_t)512 * 64 * 2);
  u16*   VcTb   = (u16*)alloc((size_t)1024 * 64 * 2);
  u16*   Wob    = (u16*)alloc((size_t)1024 * 1024 * 2);
  float* btotp  = (float*)alloc((size_t)64 * NC_ * 64 * 4);
  (void)ws_size; (void)in_sizes; (void)n_in; (void)out_size;

  ln_kernel<<<dim3(M_), dim3(256), 0, stream>>>(x, gamma, beta, xnb);
  prep_weights<<<dim3(7552), dim3(256), 0, stream>>>(
      Wq, Wk, Wv, Wa_w, Qc, Vc, Wo, Wcatb, QcTb, VcTb, Wob);
  // proj = xn @ Wcat^T : (M,704) f32   (B padded to 768 rows, col<704 guard)
  gemm_bf16<<<dim3(M_/128, 6), dim3(256), 0, stream>>>(
      xnb, Wcatb, proj, nullptr, nullptr, 704, 1024);
  split_proj<<<dim3(M_/4), dim3(256), 0, stream>>>(
      proj, Wa_b, qlatb, knf, vlatb, alphaf);
  // v = v_lat @ VcT^T : (M,1024) bf16 out
  gemm_bf16<<<dim3(M_/128, 8), dim3(256), 0, stream>>>(
      vlatb, VcTb, nullptr, nullptr, vfb, 1024, 64);
  // q = q_lat @ QcT^T : (M,512) f32 into R2 (proj dead after split_proj)
  gemm_bf16<<<dim3(M_/128, 4), dim3(256), 0, stream>>>(
      qlatb, QcTb, qf, nullptr, nullptr, 512, 64);
  scan_pass1<<<dim3(NC_-1, 64), dim3(512), 0, stream>>>(
      knf, vfb, alphaf, Sbuf, btotp);
  scan_combine<<<dim3(32, 64), dim3(256), 0, stream>>>(Sbuf, btotp);
  scan_pass2<<<dim3(NC_, 64), dim3(512), 0, stream>>>(
      qf, knf, vfb, alphaf, Sbuf, obuf);
  gemm_bf16<<<dim3(M_/128, 8), dim3(256), 0, stream>>>(
      obuf, Wob, out, x, nullptr, 1024, 1024);
}

// Round 4
// 513.075 us; speedup vs baseline: 1.1065x; 1.0146x over previous
//
#include <hip/hip_runtime.h>

typedef unsigned short u16;
typedef unsigned int   u32;
typedef __bf16 bf16x8 __attribute__((ext_vector_type(8)));
typedef float  f32x4  __attribute__((ext_vector_type(4)));
typedef float  f32x8  __attribute__((ext_vector_type(8)));

#define B_  8
#define T_  2048
#define D_  1024
#define H_  8
#define C_  64
#define DV_ 128
#define M_  (B_*T_)   // 16384
#define L_  128       // scan chunk length
#define NC_ (T_/L_)   // 16 chunks

__device__ __forceinline__ u16 f2bf(float f){
  u32 u = __float_as_uint(f);
  u32 r = (u + 0x7fffu + ((u >> 16) & 1u)) >> 16;   // RNE
  return (u16)r;
}
__device__ __forceinline__ float bf2f(u16 u){
  return __uint_as_float(((u32)u) << 16);
}

// async global->LDS, 16B per lane; LDS dest is wave-uniform base + lane*16
typedef const __attribute__((address_space(1))) unsigned int* gp1_t;
typedef __attribute__((address_space(3))) unsigned int* lp3_t;
__device__ __forceinline__ void stage16(const void* g, void* l){
  __builtin_amdgcn_global_load_lds((gp1_t)g, (lp3_t)l, 16, 0, 0);
}

// ---------------- LayerNorm: x (M,1024) f32 -> xn bf16 ----------------
__global__ __launch_bounds__(256) void ln_kernel(
    const float* __restrict__ x, const float* __restrict__ gamma,
    const float* __restrict__ beta, u16* __restrict__ xnb){
  const int m = blockIdx.x;
  const int tid = threadIdx.x;
  const int wave = tid >> 6, lane = tid & 63;
  const float* xr = x + (size_t)m * D_;
  float4 xv = *(const float4*)&xr[tid*4];
  float s = xv.x + xv.y + xv.z + xv.w;
  #pragma unroll
  for (int off = 32; off > 0; off >>= 1) s += __shfl_xor(s, off, 64);
  __shared__ float red[8];
  if (lane == 0) red[wave] = s;
  __syncthreads();
  float mu = (red[0]+red[1]+red[2]+red[3]) * (1.f/1024.f);
  float dx = xv.x-mu, dy = xv.y-mu, dz = xv.z-mu, dw = xv.w-mu;
  float ss = dx*dx + dy*dy + dz*dz + dw*dw;
  #pragma unroll
  for (int off = 32; off > 0; off >>= 1) ss += __shfl_xor(ss, off, 64);
  if (lane == 0) red[4+wave] = ss;
  __syncthreads();
  float var = (red[4]+red[5]+red[6]+red[7]) * (1.f/1024.f);
  float rs = rsqrtf(var + 1e-5f);
  float4 g  = *(const float4*)&gamma[tid*4];
  float4 bb = *(const float4*)&beta[tid*4];
  ushort4 o4;
  o4.x = f2bf(dx*rs*g.x + bb.x);
  o4.y = f2bf(dy*rs*g.y + bb.y);
  o4.z = f2bf(dz*rs*g.z + bb.z);
  o4.w = f2bf(dw*rs*g.w + bb.w);
  *(ushort4*)&xnb[(size_t)m*D_ + tid*4] = o4;
}

// ------------- weight prep: convert/concat/transpose to bf16 -------------
// Wcat is padded to 768 rows (zeros in 704..767) so the 128-wide GEMM B-tiles
// never read OOB.
__global__ __launch_bounds__(256) void prep_weights(
    const float* __restrict__ Wq, const float* __restrict__ Wk,
    const float* __restrict__ Wv, const float* __restrict__ Wa,
    const float* __restrict__ Qc, const float* __restrict__ Vc,
    const float* __restrict__ Wo,
    u16* __restrict__ Wcatb, u16* __restrict__ QcTb,
    u16* __restrict__ VcTb,  u16* __restrict__ Wob){
  int idx = blockIdx.x * 256 + threadIdx.x;
  if (idx < 786432){                       // 768*1024 (padded)
    int r = idx >> 10, col = idx & 1023;
    float v = 0.f;
    if (r < 64)       v = Wq[(size_t)r*1024 + col];
    else if (r < 128) v = Wk[(size_t)(r-64)*1024 + col];
    else if (r < 192) v = Wv[(size_t)(r-128)*1024 + col];
    else if (r < 704) v = Wa[(size_t)(r-192)*1024 + col];
    Wcatb[idx] = f2bf(v);
  } else if (idx < 819200){                // +512*64
    int i = idx - 786432;
    int n = i >> 6, c = i & 63; int h = n >> 6, e = n & 63;
    QcTb[i] = f2bf(Qc[((size_t)h*64 + c)*64 + e]);
  } else if (idx < 884736){                // +1024*64
    int i = idx - 819200;
    int n = i >> 6, c = i & 63; int h = n >> 7, d = n & 127;
    VcTb[i] = f2bf(Vc[((size_t)h*64 + c)*128 + d]);
  } else {                                 // +1024*1024 (grid = exact bound)
    int i = idx - 884736;
    Wob[i] = f2bf(Wo[i]);
  }
}

// ---- bf16 MFMA GEMM: C[M,N] = A[M,K] @ Bw[Nr,K]^T (+res) ----
// 128x128 tile, 4 waves (2x2), each wave 64x64 = 4x4 fragments, BK=32.
// Round-4 fixes vs round-3 regression:
//  (a) T21 both-sides 16B-chunk swizzle (global src chunk ^= (row>>1)&3,
//      ds_read col ^= same) -> kills the 8-way bank conflict of linear
//      [128][32] (4.19M conflict cycles measured).
//  (b) T3 minimum-2-phase: double-buffered LDS; next tile's global_load_lds
//      issued BEFORE current tile's ds_read+MFMA, one barrier per step ->
//      HBM latency overlaps ~250cyc of compute instead of being fully
//      exposed at the barrier drain.
//  (c) bijective XCD swizzle (nwg%8==0 for all our grids): each XCD gets a
//      contiguous chunk -> B-panel L2-locality.
__global__ __launch_bounds__(256) void gemm_bf16(
    const u16* __restrict__ A, const u16* __restrict__ Bw,
    float* __restrict__ C, const float* __restrict__ res,
    u16* __restrict__ Cb, int N, int K){
  __shared__ __align__(16) u16 As[2][128*32];
  __shared__ __align__(16) u16 Bs[2][128*32];
  const int tid = threadIdx.x;
  const int wave = tid >> 6;
  const int lane = tid & 63;
  const int q  = lane >> 4;
  const int mr = lane & 15;
  const int wr = wave >> 1, wc = wave & 1;

  // (c) XCD-aware bijective remap
  const int gx = gridDim.x;
  const int nlin = blockIdx.y * gx + blockIdx.x;
  const int chunk = (gx * gridDim.y) >> 3;
  const int swz = (nlin & 7) * chunk + (nlin >> 3);
  const int m0 = (swz % gx) * 128;
  const int n0 = (swz / gx) * 128;

  // staging: inst j covers tile rows [16j,16j+16); wave issues j={2w,2w+1}
  // for A and B. lane -> row lr=lane>>2, LDS 16B-slot sl=lane&3; global
  // chunk is pre-swizzled: slg = sl ^ ((lr>>1)&3)   (T21 involution)
  const int j0 = wave*2;
  const int lr = lane >> 2;
  const int slg = ((lane & 3) ^ ((lr >> 1) & 3)) * 8;
  const u16* pa0 = A  + (size_t)(m0 + (j0  )*16 + lr)*K + slg;
  const u16* pa1 = A  + (size_t)(m0 + (j0+1)*16 + lr)*K + slg;
  const u16* pb0 = Bw + (size_t)(n0 + (j0  )*16 + lr)*K + slg;
  const u16* pb1 = Bw + (size_t)(n0 + (j0+1)*16 + lr)*K + slg;
  u16* la0 = &As[0][(j0  )*512];
  u16* la1 = &As[0][(j0+1)*512];
  u16* lb0 = &Bs[0][(j0  )*512];
  u16* lb1 = &Bs[0][(j0+1)*512];
  const int bufstride = 128*32;   // u16 elements per buffer

  union FragU { uint4 u4; bf16x8 v; };
  f32x4 zero = {0.f, 0.f, 0.f, 0.f};
  f32x4 acc[4][4];
  #pragma unroll
  for (int i = 0; i < 4; i++)
    #pragma unroll
    for (int j = 0; j < 4; j++) acc[i][j] = zero;

  // fragment read: row (wr*64+mt*16+mr), 16B-chunk q ^ ((mr>>1)&3)
  const int qs = (q ^ ((mr >> 1) & 3)) * 8;
  const int aoff = (wr*64 + mr)*32 + qs;   // + mt*512
  const int boff = (wc*64 + mr)*32 + qs;

  // prologue: stage tile 0 into buffer 0
  stage16(pa0, la0); stage16(pa1, la1);
  stage16(pb0, lb0); stage16(pb1, lb1);
  __syncthreads();

  int p = 0;
  for (int k0 = 0; k0 < K; k0 += 32){
    // (b) prefetch next K-tile into the other buffer BEFORE compute
    if (k0 + 32 < K){
      int pn = p ^ 1;
      stage16(pa0 + k0 + 32, la0 + pn*bufstride);
      stage16(pa1 + k0 + 32, la1 + pn*bufstride);
      stage16(pb0 + k0 + 32, lb0 + pn*bufstride);
      stage16(pb1 + k0 + 32, lb1 + pn*bufstride);
    }
    bf16x8 afr[4], bfr[4];
    #pragma unroll
    for (int mt = 0; mt < 4; mt++){
      FragU f; f.u4 = *(const uint4*)(&As[p][aoff + mt*512]);
      afr[mt] = f.v;
    }
    #pragma unroll
    for (int nt = 0; nt < 4; nt++){
      FragU f; f.u4 = *(const uint4*)(&Bs[p][boff + nt*512]);
      bfr[nt] = f.v;
    }
    #pragma unroll
    for (int mt = 0; mt < 4; mt++)
      #pragma unroll
      for (int nt = 0; nt < 4; nt++)
        acc[mt][nt] = __builtin_amdgcn_mfma_f32_16x16x32_bf16(
            afr[mt], bfr[nt], acc[mt][nt], 0, 0, 0);
    __syncthreads();   // drains vmcnt(0): prefetched tile resident; all
                       // ds_reads of buf[p] complete -> safe to overwrite
    p ^= 1;
  }

  #pragma unroll
  for (int mt = 0; mt < 4; mt++)
    #pragma unroll
    for (int nt = 0; nt < 4; nt++){
      int col = n0 + wc*64 + nt*16 + mr;
      if (col < N){
        #pragma unroll
        for (int r = 0; r < 4; r++){
          int row = m0 + wr*64 + mt*16 + q*4 + r;
          size_t idx = (size_t)row * N + col;
          float v = acc[mt][nt][r];
          if (res) v += res[idx];
          if (Cb) Cb[idx] = f2bf(v);
          else    C[idx] = v;
        }
      }
    }
}

// ------------- split proj (M x 704) -------------
__global__ __launch_bounds__(256) void split_proj(
    const float* __restrict__ proj, const float* __restrict__ Wab,
    u16* __restrict__ qlatb, float* __restrict__ knf,
    u16* __restrict__ vlatb, float* __restrict__ alphaf){
  const int m = blockIdx.x * 4 + (threadIdx.x >> 6);
  const int lane = threadIdx.x & 63;
  const float* pr = proj + (size_t)m * 704;
  qlatb[(size_t)m*64 + lane] = f2bf(pr[lane]);
  float kv = pr[64 + lane];
  float ss = kv * kv;
  #pragma unroll
  for (int off = 32; off > 0; off >>= 1) ss += __shfl_xor(ss, off, 64);
  float nrm = fmaxf(sqrtf(ss), 1e-12f);
  knf[(size_t)m*64 + lane] = kv / nrm;
  vlatb[(size_t)m*64 + lane] = f2bf(pr[128 + lane]);
  #pragma unroll
  for (int j = 0; j < 8; j++){
    int jj = j*64 + lane;
    float av = pr[192 + jj] + Wab[jj];
    alphaf[(size_t)m*512 + jj] = 1.f / (1.f + expf(-av));
  }
}

// ===================== blocked two-pass gated scan =====================
// 512 threads = 8 waves. wave w owns channel slice [8w, 8w+8); lane dg owns
// value columns {2dg, 2dg+1}. a/k/q are wave-uniform -> SGPRs via
// s_load_dwordx8 (2 timesteps per lgkmcnt(0) to amortize SMEM latency).

__global__ __launch_bounds__(512, 8) void scan_pass1(
    const float* __restrict__ knf, const u16* __restrict__ vb,
    const float* __restrict__ alphaf,
    float* __restrict__ Sbuf, float* __restrict__ btot){
  const int ch = blockIdx.x;        // 0..NC_-2 (last chunk's state unused)
  const int bh = blockIdx.y;
  const int b = bh >> 3, h = bh & 7;
  const int tid = threadIdx.x;
  const int w = __builtin_amdgcn_readfirstlane(tid >> 6);  // wave = ch-group
  const int dg = tid & 63;
  const int t0 = ch * L_;

  const float* kp  = knf    + ((size_t)(b*T_ + t0))*64  + w*8;
  const float* ap  = alphaf + ((size_t)(b*T_ + t0))*512 + h*64 + w*8;
  const float* alp = ap + (dg & 7);            // per-lane alpha for btot
  const u32*   vp  = (const u32*)(vb + ((size_t)(b*T_ + t0))*1024 + h*128) + dg;

  float S[8][2];
  #pragma unroll
  for (int j = 0; j < 8; j++){ S[j][0] = 0.f; S[j][1] = 0.f; }
  float bt = 1.f;

  for (int t = 0; t < L_; t += 2){
    f32x8 a0, a1, k0, k1;
    asm volatile(
      "s_load_dwordx8 %0, %4, 0x0\n\t"
      "s_load_dwordx8 %1, %4, 0x800\n\t"
      "s_load_dwordx8 %2, %5, 0x0\n\t"
      "s_load_dwordx8 %3, %5, 0x100\n\t"
      "s_waitcnt lgkmcnt(0)"
      : "=&s"(a0), "=&s"(a1), "=&s"(k0), "=&s"(k1)
      : "s"(ap), "s"(kp));
    float al0 = alp[0], al1 = alp[512];
    u32 vv0 = vp[0], vv1 = vp[512];
    float v00 = __uint_as_float(vv0 << 16);
    float v01 = __uint_as_float(vv0 & 0xffff0000u);
    float v10 = __uint_as_float(vv1 << 16);
    float v11 = __uint_as_float(vv1 & 0xffff0000u);
    #pragma unroll
    for (int j = 0; j < 8; j++){
      S[j][0] = a0[j]*S[j][0] + k0[j]*v00;
      S[j][1] = a0[j]*S[j][1] + k0[j]*v01;
    }
    bt *= al0;
    #pragma unroll
    for (int j = 0; j < 8; j++){
      S[j][0] = a1[j]*S[j][0] + k1[j]*v10;
      S[j][1] = a1[j]*S[j][1] + k1[j]*v11;
    }
    bt *= al1;
    ap += 1024; kp += 128; alp += 1024; vp += 1024;
  }

  float* Sl = Sbuf + ((size_t)bh*NC_ + ch) * (64*128);
  #pragma unroll
  for (int j = 0; j < 8; j++)
    *(float2*)&Sl[(size_t)(w*8+j)*128 + 2*dg] = make_float2(S[j][0], S[j][1]);
  if (dg < 8) btot[((size_t)bh*NC_ + ch)*64 + w*8 + dg] = bt;
}

// in-place: Sbuf[ch] (local states) -> Sbuf[ch] (prefix init states)
// element-parallel: grid (32, 64), one element per thread, serial over chunks
__global__ __launch_bounds__(256) void scan_combine(
    float* __restrict__ Sbuf, const float* __restrict__ btot){
  const int bh = blockIdx.y;
  const int e  = blockIdx.x * 256 + threadIdx.x;   // 0..8191
  float*       Sb  = Sbuf + (size_t)bh*NC_*8192 + e;
  const float* btb = btot + (size_t)bh*NC_*64 + (e >> 7);
  float S = 0.f;
  #pragma unroll
  for (int j = 0; j < NC_; j++){
    float loc = Sb[(size_t)j*8192];
    Sb[(size_t)j*8192] = S;
    if (j < NC_-1) S = btb[j*64] * S + loc;
  }
}

__global__ __launch_bounds__(512, 8) void scan_pass2(
    const float* __restrict__ qf, const float* __restrict__ knf,
    const u16* __restrict__ vb, const float* __restrict__ alphaf,
    const float* __restrict__ Sbuf, u16* __restrict__ ob){
  const int ch = blockIdx.x;        // 0..NC_-1
  const int bh = blockIdx.y;
  const int b = bh >> 3, h = bh & 7;
  const int tid = threadIdx.x;
  const int w = __builtin_amdgcn_readfirstlane(tid >> 6);  // wave = ch-group
  const int dg = tid & 63;
  const int t0 = ch * L_;
  __shared__ __align__(16) float sO[2][8][4][128];   // 32 KB, double-buffered

  const float* qp = qf     + ((size_t)(b*T_ + t0))*512 + h*64 + w*8;
  const float* kp = knf    + ((size_t)(b*T_ + t0))*64  + w*8;
  const float* ap = alphaf + ((size_t)(b*T_ + t0))*512 + h*64 + w*8;
  const u32*   vp = (const u32*)(vb + ((size_t)(b*T_ + t0))*1024 + h*128) + dg;
  u16* obase = ob + ((size_t)(b*T_ + t0))*1024 + h*128;

  float S[8][2];
  const float* Si = Sbuf + ((size_t)bh*NC_ + ch) * (64*128);
  #pragma unroll
  for (int j = 0; j < 8; j++){
    float2 s2 = *(const float2*)&Si[(size_t)(w*8+j)*128 + 2*dg];
    S[j][0] = s2.x; S[j][1] = s2.y;
  }

  const int rtt = tid >> 7, rdd = tid & 127;   // reduction mapping (4tt x 128d)

  for (int sb = 0; sb < L_/4; sb++){
    const int p = sb & 1;
    #pragma unroll
    for (int half = 0; half < 2; half++){
      f32x8 a0, a1, k0, k1, q0, q1;
      asm volatile(
        "s_load_dwordx8 %0, %6, 0x0\n\t"
        "s_load_dwordx8 %1, %6, 0x800\n\t"
        "s_load_dwordx8 %2, %7, 0x0\n\t"
        "s_load_dwordx8 %3, %7, 0x100\n\t"
        "s_load_dwordx8 %4, %8, 0x0\n\t"
        "s_load_dwordx8 %5, %8, 0x800\n\t"
        "s_waitcnt lgkmcnt(0)"
        : "=&s"(a0), "=&s"(a1), "=&s"(k0), "=&s"(k1), "=&s"(q0), "=&s"(q1)
        : "s"(ap), "s"(kp), "s"(qp));
      u32 vv0 = vp[0], vv1 = vp[512];
      float v00 = __uint_as_float(vv0 << 16);
      float v01 = __uint_as_float(vv0 & 0xffff0000u);
      float v10 = __uint_as_float(vv1 << 16);
      float v11 = __uint_as_float(vv1 & 0xffff0000u);
      // ---- tt0 of pair ----
      {
        float oa0, oa1, ob0, ob1;          // 2 accum chains per column
        S[0][0] = a0[0]*S[0][0] + k0[0]*v00;  oa0 = S[0][0]*q0[0];
        S[0][1] = a0[0]*S[0][1] + k0[0]*v01;  oa1 = S[0][1]*q0[0];
        S[1][0] = a0[1]*S[1][0] + k0[1]*v00;  ob0 = S[1][0]*q0[1];
        S[1][1] = a0[1]*S[1][1] + k0[1]*v01;  ob1 = S[1][1]*q0[1];
        #pragma unroll
        for (int j = 2; j < 8; j += 2){
          S[j][0]   = a0[j]*S[j][0]     + k0[j]*v00;    oa0 += S[j][0]*q0[j];
          S[j][1]   = a0[j]*S[j][1]     + k0[j]*v01;    oa1 += S[j][1]*q0[j];
          S[j+1][0] = a0[j+1]*S[j+1][0] + k0[j+1]*v00;  ob0 += S[j+1][0]*q0[j+1];
          S[j+1][1] = a0[j+1]*S[j+1][1] + k0[j+1]*v01;  ob1 += S[j+1][1]*q0[j+1];
        }
        *(float2*)&sO[p][w][half*2+0][2*dg] = make_float2(oa0+ob0, oa1+ob1);
      }
      // ---- tt1 of pair ----
      {
        float oa0, oa1, ob0, ob1;
        S[0][0] = a1[0]*S[0][0] + k1[0]*v10;  oa0 = S[0][0]*q1[0];
        S[0][1] = a1[0]*S[0][1] + k1[0]*v11;  oa1 = S[0][1]*q1[0];
        S[1][0] = a1[1]*S[1][0] + k1[1]*v10;  ob0 = S[1][0]*q1[1];
        S[1][1] = a1[1]*S[1][1] + k1[1]*v11;  ob1 = S[1][1]*q1[1];
        #pragma unroll
        for (int j = 2; j < 8; j += 2){
          S[j][0]   = a1[j]*S[j][0]     + k1[j]*v10;    oa0 += S[j][0]*q1[j];
          S[j][1]   = a1[j]*S[j][1]     + k1[j]*v11;    oa1 += S[j][1]*q1[j];
          S[j+1][0] = a1[j+1]*S[j+1][0] + k1[j+1]*v10;  ob0 += S[j+1][0]*q1[j+1];
          S[j+1][1] = a1[j+1]*S[j+1][1] + k1[j+1]*v11;  ob1 += S[j+1][1]*q1[j+1];
        }
        *(float2*)&sO[p][w][half*2+1][2*dg] = make_float2(oa0+ob0, oa1+ob1);
      }
      ap += 1024; kp += 128; qp += 1024; vp += 1024;
    }
    __syncthreads();
    // reduce 8 wave-partials; double-buffered sO -> next sb writes hit p^1,
    // so no second barrier is needed.
    float o = sO[p][0][rtt][rdd] + sO[p][1][rtt][rdd]
            + sO[p][2][rtt][rdd] + sO[p][3][rtt][rdd]
            + sO[p][4][rtt][rdd] + sO[p][5][rtt][rdd]
            + sO[p][6][rtt][rdd] + sO[p][7][rtt][rdd];
    obase[(size_t)(sb*4 + rtt)*1024 + rdd] = f2bf(o);
  }
}

// ----------------------------- launch -----------------------------
extern "C" void kernel_launch(void* const* d_in, const int* in_sizes, int n_in,
                              void* d_out, int out_size, void* d_ws, size_t ws_size,
                              hipStream_t stream){
  const float* x     = (const float*)d_in[0];
  const float* Wq    = (const float*)d_in[1];
  const float* Wk    = (const float*)d_in[2];
  const float* Wv    = (const float*)d_in[3];
  const float* Qc    = (const float*)d_in[4];
  const float* Vc    = (const float*)d_in[5];
  const float* Wa_w  = (const float*)d_in[6];
  const float* Wa_b  = (const float*)d_in[7];
  const float* Wo    = (const float*)d_in[8];
  const float* gamma = (const float*)d_in[9];
  const float* beta  = (const float*)d_in[10];
  float* out = (float*)d_out;

  char* ws = (char*)d_ws;
  size_t off = 0;
  auto alloc = [&](size_t bytes) -> void* {
    void* p = ws + off; off += (bytes + 255) & ~(size_t)255; return p;
  };
  // R1: xnb (bf16 M*1024) -> obuf (bf16 M*1024)
  char* R1 = (char*)alloc((size_t)M_ * 1024 * 2);
  u16*   xnb  = (u16*)R1;
  u16*   obuf = (u16*)R1;
  // R2: proj (f32 M*704) -> qf (f32 M*512)
  char* R2 = (char*)alloc((size_t)M_ * 704 * 4);
  float* proj = (float*)R2;
  float* qf   = (float*)R2;
  float* Sbuf   = (float*)alloc((size_t)64 * NC_ * 8192 * 4);   // 33.5 MB
  u16*   vfb    = (u16*)alloc((size_t)M_ * 1024 * 2);           // v bf16
  float* alphaf = (float*)alloc((size_t)M_ * 512 * 4);
  float* knf    = (float*)alloc((size_t)M_ * 64 * 4);
  u16*   qlatb  = (u16*)alloc((size_t)M_ * 64 * 2);
  u16*   vlatb  = (u16*)alloc((size_t)M_ * 64 * 2);
  u16*   Wcatb  = (u16*)alloc((size_t)768 * 1024 * 2);          // padded to 768
  u16*   QcTb   = (u16*)alloc((size_t)512 * 64 * 2);
  u16*   VcTb   = (u16*)alloc((size_t)1024 * 64 * 2);
  u16*   Wob    = (u16*)alloc((size_t)1024 * 1024 * 2);
  float* btotp  = (float*)alloc((size_t)64 * NC_ * 64 * 4);
  (void)ws_size; (void)in_sizes; (void)n_in; (void)out_size;

  ln_kernel<<<dim3(M_), dim3(256), 0, stream>>>(x, gamma, beta, xnb);
  prep_weights<<<dim3(7552), dim3(256), 0, stream>>>(
      Wq, Wk, Wv, Wa_w, Qc, Vc, Wo, Wcatb, QcTb, VcTb, Wob);
  // proj = xn @ Wcat^T : (M,704) f32   (B padded to 768 rows, col<704 guard)
  gemm_bf16<<<dim3(M_/128, 6), dim3(256), 0, stream>>>(
      xnb, Wcatb, proj, nullptr, nullptr, 704, 1024);
  split_proj<<<dim3(M_/4), dim3(256), 0, stream>>>(
      proj, Wa_b, qlatb, knf, vlatb, alphaf);
  // v = v_lat @ VcT^T : (M,1024) bf16 out
  gemm_bf16<<<dim3(M_/128, 8), dim3(256), 0, stream>>>(
      vlatb, VcTb, nullptr, nullptr, vfb, 1024, 64);
  // q = q_lat @ QcT^T : (M,512) f32 into R2 (proj dead after split_proj)
  gemm_bf16<<<dim3(M_/128, 4), dim3(256), 0, stream>>>(
      qlatb, QcTb, qf, nullptr, nullptr, 512, 64);
  scan_pass1<<<dim3(NC_-1, 64), dim3(512), 0, stream>>>(
      knf, vfb, alphaf, Sbuf, btotp);
  scan_combine<<<dim3(32, 64), dim3(256), 0, stream>>>(Sbuf, btotp);
  scan_pass2<<<dim3(NC_, 64), dim3(512), 0, stream>>>(
      qf, knf, vfb, alphaf, Sbuf, obuf);
  gemm_bf16<<<dim3(M_/128, 8), dim3(256), 0, stream>>>(
      obuf, Wob, out, x, nullptr, 1024, 1024);
}

// Round 5
// 510.023 us; speedup vs baseline: 1.1132x; 1.0060x over previous
//
#include <hip/hip_runtime.h>

typedef unsigned short u16;
typedef unsigned int   u32;
typedef __bf16 bf16x8 __attribute__((ext_vector_type(8)));
typedef float  f32x4  __attribute__((ext_vector_type(4)));
typedef float  f32x8  __attribute__((ext_vector_type(8)));

#define B_  8
#define T_  2048
#define D_  1024
#define H_  8
#define C_  64
#define DV_ 128
#define M_  (B_*T_)   // 16384
#define L_  128       // scan chunk length
#define NC_ (T_/L_)   // 16 chunks

__device__ __forceinline__ u16 f2bf(float f){
  u32 u = __float_as_uint(f);
  u32 r = (u + 0x7fffu + ((u >> 16) & 1u)) >> 16;   // RNE
  return (u16)r;
}
__device__ __forceinline__ float bf2f(u16 u){
  return __uint_as_float(((u32)u) << 16);
}

// async global->LDS, 16B per lane; LDS dest is wave-uniform base + lane*16
typedef const __attribute__((address_space(1))) unsigned int* gp1_t;
typedef __attribute__((address_space(3))) unsigned int* lp3_t;
__device__ __forceinline__ void stage16(const void* g, void* l){
  __builtin_amdgcn_global_load_lds((gp1_t)g, (lp3_t)l, 16, 0, 0);
}

// counted-vmcnt + raw barrier (T3/T4): immediate N, memory-fenced both sides
#define VMCNT(N) asm volatile("s_waitcnt vmcnt(" #N ")" ::: "memory")
#define SBAR() do{ asm volatile("" ::: "memory"); \
                   __builtin_amdgcn_sched_barrier(0); \
                   __builtin_amdgcn_s_barrier(); \
                   __builtin_amdgcn_sched_barrier(0); \
                   asm volatile("" ::: "memory"); }while(0)

// ---------------- LayerNorm: x (M,1024) f32 -> xn bf16 ----------------
__global__ __launch_bounds__(256) void ln_kernel(
    const float* __restrict__ x, const float* __restrict__ gamma,
    const float* __restrict__ beta, u16* __restrict__ xnb){
  const int m = blockIdx.x;
  const int tid = threadIdx.x;
  const int wave = tid >> 6, lane = tid & 63;
  const float* xr = x + (size_t)m * D_;
  float4 xv = *(const float4*)&xr[tid*4];
  float s = xv.x + xv.y + xv.z + xv.w;
  #pragma unroll
  for (int off = 32; off > 0; off >>= 1) s += __shfl_xor(s, off, 64);
  __shared__ float red[8];
  if (lane == 0) red[wave] = s;
  __syncthreads();
  float mu = (red[0]+red[1]+red[2]+red[3]) * (1.f/1024.f);
  float dx = xv.x-mu, dy = xv.y-mu, dz = xv.z-mu, dw = xv.w-mu;
  float ss = dx*dx + dy*dy + dz*dz + dw*dw;
  #pragma unroll
  for (int off = 32; off > 0; off >>= 1) ss += __shfl_xor(ss, off, 64);
  if (lane == 0) red[4+wave] = ss;
  __syncthreads();
  float var = (red[4]+red[5]+red[6]+red[7]) * (1.f/1024.f);
  float rs = rsqrtf(var + 1e-5f);
  float4 g  = *(const float4*)&gamma[tid*4];
  float4 bb = *(const float4*)&beta[tid*4];
  ushort4 o4;
  o4.x = f2bf(dx*rs*g.x + bb.x);
  o4.y = f2bf(dy*rs*g.y + bb.y);
  o4.z = f2bf(dz*rs*g.z + bb.z);
  o4.w = f2bf(dw*rs*g.w + bb.w);
  *(ushort4*)&xnb[(size_t)m*D_ + tid*4] = o4;
}

// ------------- weight prep: convert/concat/transpose to bf16 -------------
// Wcat is padded to 768 rows (zeros in 704..767) so the 128-wide GEMM B-tiles
// never read OOB.
__global__ __launch_bounds__(256) void prep_weights(
    const float* __restrict__ Wq, const float* __restrict__ Wk,
    const float* __restrict__ Wv, const float* __restrict__ Wa,
    const float* __restrict__ Qc, const float* __restrict__ Vc,
    const float* __restrict__ Wo,
    u16* __restrict__ Wcatb, u16* __restrict__ QcTb,
    u16* __restrict__ VcTb,  u16* __restrict__ Wob){
  int idx = blockIdx.x * 256 + threadIdx.x;
  if (idx < 786432){                       // 768*1024 (padded)
    int r = idx >> 10, col = idx & 1023;
    float v = 0.f;
    if (r < 64)       v = Wq[(size_t)r*1024 + col];
    else if (r < 128) v = Wk[(size_t)(r-64)*1024 + col];
    else if (r < 192) v = Wv[(size_t)(r-128)*1024 + col];
    else if (r < 704) v = Wa[(size_t)(r-192)*1024 + col];
    Wcatb[idx] = f2bf(v);
  } else if (idx < 819200){                // +512*64
    int i = idx - 786432;
    int n = i >> 6, c = i & 63; int h = n >> 6, e = n & 63;
    QcTb[i] = f2bf(Qc[((size_t)h*64 + c)*64 + e]);
  } else if (idx < 884736){                // +1024*64
    int i = idx - 819200;
    int n = i >> 6, c = i & 63; int h = n >> 7, d = n & 127;
    VcTb[i] = f2bf(Vc[((size_t)h*64 + c)*128 + d]);
  } else {                                 // +1024*1024 (grid = exact bound)
    int i = idx - 884736;
    Wob[i] = f2bf(Wo[i]);
  }
}

// ---- bf16 MFMA GEMM: C[M,N] = A[M,K] @ Bw[Nr,K]^T (+res) ----
// 128x128 tile, 4 waves (2x2), each wave 64x64 = 4x4 fragments, BK=32.
// Round-5 structure (T3+T4): TRIPLE-buffered LDS, counted vmcnt (8/4/0,
// never 0 in steady state), raw s_barrier. Tile i+2's global_load_lds are
// issued at step i and stay in flight across TWO compute steps (~600-700cyc)
// -> HBM/L3 latency fully hidden; the barrier no longer drains the staging
// queue (the round-3/4 vmcnt(0)-drain was the measured 10%-MfmaUtil stall).
// Safety: barrier after each wave's counted wait => all waves' tile-i loads
// retired => whole tile visible; 2nd barrier (reads consumed by MFMA before
// it) gates buffer overwrite two steps later.
// T21 16B-chunk XOR swizzle kept (round-4: conflicts 4.19M -> 0).
// XCD remap REMOVED (round-4: it inflated FETCH 78.5->166 MB; natural
// x-major order already shares B-panels between consecutive blocks).
__global__ __launch_bounds__(256) void gemm_bf16(
    const u16* __restrict__ A, const u16* __restrict__ Bw,
    float* __restrict__ C, const float* __restrict__ res,
    u16* __restrict__ Cb, int N, int K){
  __shared__ __align__(16) u16 As[3][128*32];
  __shared__ __align__(16) u16 Bs[3][128*32];
  const int tid = threadIdx.x;
  const int wave = tid >> 6;
  const int lane = tid & 63;
  const int q  = lane >> 4;
  const int mr = lane & 15;
  const int wr = wave >> 1, wc = wave & 1;
  const int m0 = blockIdx.x * 128;
  const int n0 = blockIdx.y * 128;

  // staging: inst j covers tile rows [16j,16j+16); wave issues j={2w,2w+1}
  // for A and B. lane -> row lr=lane>>2, LDS 16B-slot lane&3; global chunk
  // pre-swizzled: slg = (lane&3) ^ ((lr>>1)&3)   (T21 involution)
  const int j0 = wave*2;
  const int lr = lane >> 2;
  const int slg = ((lane & 3) ^ ((lr >> 1) & 3)) * 8;
  const u16* pa0 = A  + (size_t)(m0 + (j0  )*16 + lr)*K + slg;
  const u16* pa1 = A  + (size_t)(m0 + (j0+1)*16 + lr)*K + slg;
  const u16* pb0 = Bw + (size_t)(n0 + (j0  )*16 + lr)*K + slg;
  const u16* pb1 = Bw + (size_t)(n0 + (j0+1)*16 + lr)*K + slg;

  union FragU { uint4 u4; bf16x8 v; };
  f32x4 zero = {0.f, 0.f, 0.f, 0.f};
  f32x4 acc[4][4];
  #pragma unroll
  for (int i = 0; i < 4; i++)
    #pragma unroll
    for (int j = 0; j < 4; j++) acc[i][j] = zero;

  // fragment read: row (wr*64+mt*16+mr), 16B-chunk q ^ ((mr>>1)&3)
  const int qs = (q ^ ((mr >> 1) & 3)) * 8;
  const int aoff = (wr*64 + mr)*32 + qs;   // + mt*512
  const int boff = (wc*64 + mr)*32 + qs;

  auto stage_tile = [&](int t, int b){
    int off = t*32;
    stage16(pa0 + off, &As[b][(j0  )*512]);
    stage16(pa1 + off, &As[b][(j0+1)*512]);
    stage16(pb0 + off, &Bs[b][(j0  )*512]);
    stage16(pb1 + off, &Bs[b][(j0+1)*512]);
  };
  auto compute = [&](int b){
    bf16x8 afr[4], bfr[4];
    #pragma unroll
    for (int mt = 0; mt < 4; mt++){
      FragU f; f.u4 = *(const uint4*)(&As[b][aoff + mt*512]);
      afr[mt] = f.v;
    }
    #pragma unroll
    for (int nt2 = 0; nt2 < 4; nt2++){
      FragU f; f.u4 = *(const uint4*)(&Bs[b][boff + nt2*512]);
      bfr[nt2] = f.v;
    }
    #pragma unroll
    for (int mt = 0; mt < 4; mt++)
      #pragma unroll
      for (int nt2 = 0; nt2 < 4; nt2++)
        acc[mt][nt2] = __builtin_amdgcn_mfma_f32_16x16x32_bf16(
            afr[mt], bfr[nt2], acc[mt][nt2], 0, 0, 0);
  };

  const int nt = K >> 5;                  // K-tiles (>=2 for all our calls)
  // prologue: tiles 0,1 in flight
  stage_tile(0, 0);
  if (nt > 1) stage_tile(1, 1);

  int bcur = 0;   // buffer holding tile i
  int bst  = 2;   // buffer receiving tile i+2
  for (int i = 0; i < nt-2; i++){
    stage_tile(i+2, bst);
    VMCNT(8);                 // tiles i+1,i+2 may stay in flight; tile i done
    SBAR();
    compute(bcur);
    SBAR();                   // all waves done reading buf bcur
    bcur = (bcur == 2) ? 0 : bcur + 1;
    bst  = (bst  == 2) ? 0 : bst  + 1;
  }
  if (nt >= 2){
    VMCNT(4);                 // tile nt-1 may stay in flight; tile nt-2 done
    SBAR();
    compute(bcur);
    SBAR();
    bcur = (bcur == 2) ? 0 : bcur + 1;
  }
  VMCNT(0);
  SBAR();
  compute(bcur);

  #pragma unroll
  for (int mt = 0; mt < 4; mt++)
    #pragma unroll
    for (int nt2 = 0; nt2 < 4; nt2++){
      int col = n0 + wc*64 + nt2*16 + mr;
      if (col < N){
        #pragma unroll
        for (int r = 0; r < 4; r++){
          int row = m0 + wr*64 + mt*16 + q*4 + r;
          size_t idx = (size_t)row * N + col;
          float v = acc[mt][nt2][r];
          if (res) v += res[idx];
          if (Cb) Cb[idx] = f2bf(v);
          else    C[idx] = v;
        }
      }
    }
}

// ------------- split proj (M x 704) -------------
__global__ __launch_bounds__(256) void split_proj(
    const float* __restrict__ proj, const float* __restrict__ Wab,
    u16* __restrict__ qlatb, float* __restrict__ knf,
    u16* __restrict__ vlatb, float* __restrict__ alphaf){
  const int m = blockIdx.x * 4 + (threadIdx.x >> 6);
  const int lane = threadIdx.x & 63;
  const float* pr = proj + (size_t)m * 704;
  qlatb[(size_t)m*64 + lane] = f2bf(pr[lane]);
  float kv = pr[64 + lane];
  float ss = kv * kv;
  #pragma unroll
  for (int off = 32; off > 0; off >>= 1) ss += __shfl_xor(ss, off, 64);
  float nrm = fmaxf(sqrtf(ss), 1e-12f);
  knf[(size_t)m*64 + lane] = kv / nrm;
  vlatb[(size_t)m*64 + lane] = f2bf(pr[128 + lane]);
  #pragma unroll
  for (int j = 0; j < 8; j++){
    int jj = j*64 + lane;
    float av = pr[192 + jj] + Wab[jj];
    alphaf[(size_t)m*512 + jj] = 1.f / (1.f + expf(-av));
  }
}

// ===================== blocked two-pass gated scan =====================
// 512 threads = 8 waves. wave w owns channel slice [8w, 8w+8); lane dg owns
// value columns {2dg, 2dg+1}. a/k/q are wave-uniform -> SGPRs via
// s_load_dwordx8 (2 timesteps per lgkmcnt(0) to amortize SMEM latency).

__global__ __launch_bounds__(512, 8) void scan_pass1(
    const float* __restrict__ knf, const u16* __restrict__ vb,
    const float* __restrict__ alphaf,
    float* __restrict__ Sbuf, float* __restrict__ btot){
  const int ch = blockIdx.x;        // 0..NC_-2 (last chunk's state unused)
  const int bh = blockIdx.y;
  const int b = bh >> 3, h = bh & 7;
  const int tid = threadIdx.x;
  const int w = __builtin_amdgcn_readfirstlane(tid >> 6);  // wave = ch-group
  const int dg = tid & 63;
  const int t0 = ch * L_;

  const float* kp  = knf    + ((size_t)(b*T_ + t0))*64  + w*8;
  const float* ap  = alphaf + ((size_t)(b*T_ + t0))*512 + h*64 + w*8;
  const float* alp = ap + (dg & 7);            // per-lane alpha for btot
  const u32*   vp  = (const u32*)(vb + ((size_t)(b*T_ + t0))*1024 + h*128) + dg;

  float S[8][2];
  #pragma unroll
  for (int j = 0; j < 8; j++){ S[j][0] = 0.f; S[j][1] = 0.f; }
  float bt = 1.f;

  for (int t = 0; t < L_; t += 2){
    f32x8 a0, a1, k0, k1;
    asm volatile(
      "s_load_dwordx8 %0, %4, 0x0\n\t"
      "s_load_dwordx8 %1, %4, 0x800\n\t"
      "s_load_dwordx8 %2, %5, 0x0\n\t"
      "s_load_dwordx8 %3, %5, 0x100\n\t"
      "s_waitcnt lgkmcnt(0)"
      : "=&s"(a0), "=&s"(a1), "=&s"(k0), "=&s"(k1)
      : "s"(ap), "s"(kp));
    float al0 = alp[0], al1 = alp[512];
    u32 vv0 = vp[0], vv1 = vp[512];
    float v00 = __uint_as_float(vv0 << 16);
    float v01 = __uint_as_float(vv0 & 0xffff0000u);
    float v10 = __uint_as_float(vv1 << 16);
    float v11 = __uint_as_float(vv1 & 0xffff0000u);
    #pragma unroll
    for (int j = 0; j < 8; j++){
      S[j][0] = a0[j]*S[j][0] + k0[j]*v00;
      S[j][1] = a0[j]*S[j][1] + k0[j]*v01;
    }
    bt *= al0;
    #pragma unroll
    for (int j = 0; j < 8; j++){
      S[j][0] = a1[j]*S[j][0] + k1[j]*v10;
      S[j][1] = a1[j]*S[j][1] + k1[j]*v11;
    }
    bt *= al1;
    ap += 1024; kp += 128; alp += 1024; vp += 1024;
  }

  float* Sl = Sbuf + ((size_t)bh*NC_ + ch) * (64*128);
  #pragma unroll
  for (int j = 0; j < 8; j++)
    *(float2*)&Sl[(size_t)(w*8+j)*128 + 2*dg] = make_float2(S[j][0], S[j][1]);
  if (dg < 8) btot[((size_t)bh*NC_ + ch)*64 + w*8 + dg] = bt;
}

// in-place: Sbuf[ch] (local states) -> Sbuf[ch] (prefix init states)
// element-parallel: grid (32, 64), one element per thread, serial over chunks
__global__ __launch_bounds__(256) void scan_combine(
    float* __restrict__ Sbuf, const float* __restrict__ btot){
  const int bh = blockIdx.y;
  const int e  = blockIdx.x * 256 + threadIdx.x;   // 0..8191
  float*       Sb  = Sbuf + (size_t)bh*NC_*8192 + e;
  const float* btb = btot + (size_t)bh*NC_*64 + (e >> 7);
  float S = 0.f;
  #pragma unroll
  for (int j = 0; j < NC_; j++){
    float loc = Sb[(size_t)j*8192];
    Sb[(size_t)j*8192] = S;
    if (j < NC_-1) S = btb[j*64] * S + loc;
  }
}

__global__ __launch_bounds__(512, 8) void scan_pass2(
    const float* __restrict__ qf, const float* __restrict__ knf,
    const u16* __restrict__ vb, const float* __restrict__ alphaf,
    const float* __restrict__ Sbuf, u16* __restrict__ ob){
  const int ch = blockIdx.x;        // 0..NC_-1
  const int bh = blockIdx.y;
  const int b = bh >> 3, h = bh & 7;
  const int tid = threadIdx.x;
  const int w = __builtin_amdgcn_readfirstlane(tid >> 6);  // wave = ch-group
  const int dg = tid & 63;
  const int t0 = ch * L_;
  __shared__ __align__(16) float sO[2][8][4][128];   // 32 KB, double-buffered

  const float* qp = qf     + ((size_t)(b*T_ + t0))*512 + h*64 + w*8;
  const float* kp = knf    + ((size_t)(b*T_ + t0))*64  + w*8;
  const float* ap = alphaf + ((size_t)(b*T_ + t0))*512 + h*64 + w*8;
  const u32*   vp = (const u32*)(vb + ((size_t)(b*T_ + t0))*1024 + h*128) + dg;
  u16* obase = ob + ((size_t)(b*T_ + t0))*1024 + h*128;

  float S[8][2];
  const float* Si = Sbuf + ((size_t)bh*NC_ + ch) * (64*128);
  #pragma unroll
  for (int j = 0; j < 8; j++){
    float2 s2 = *(const float2*)&Si[(size_t)(w*8+j)*128 + 2*dg];
    S[j][0] = s2.x; S[j][1] = s2.y;
  }

  const int rtt = tid >> 7, rdd = tid & 127;   // reduction mapping (4tt x 128d)

  for (int sb = 0; sb < L_/4; sb++){
    const int p = sb & 1;
    #pragma unroll
    for (int half = 0; half < 2; half++){
      f32x8 a0, a1, k0, k1, q0, q1;
      asm volatile(
        "s_load_dwordx8 %0, %6, 0x0\n\t"
        "s_load_dwordx8 %1, %6, 0x800\n\t"
        "s_load_dwordx8 %2, %7, 0x0\n\t"
        "s_load_dwordx8 %3, %7, 0x100\n\t"
        "s_load_dwordx8 %4, %8, 0x0\n\t"
        "s_load_dwordx8 %5, %8, 0x800\n\t"
        "s_waitcnt lgkmcnt(0)"
        : "=&s"(a0), "=&s"(a1), "=&s"(k0), "=&s"(k1), "=&s"(q0), "=&s"(q1)
        : "s"(ap), "s"(kp), "s"(qp));
      u32 vv0 = vp[0], vv1 = vp[512];
      float v00 = __uint_as_float(vv0 << 16);
      float v01 = __uint_as_float(vv0 & 0xffff0000u);
      float v10 = __uint_as_float(vv1 << 16);
      float v11 = __uint_as_float(vv1 & 0xffff0000u);
      // ---- tt0 of pair ----
      {
        float oa0, oa1, ob0, ob1;          // 2 accum chains per column
        S[0][0] = a0[0]*S[0][0] + k0[0]*v00;  oa0 = S[0][0]*q0[0];
        S[0][1] = a0[0]*S[0][1] + k0[0]*v01;  oa1 = S[0][1]*q0[0];
        S[1][0] = a0[1]*S[1][0] + k0[1]*v00;  ob0 = S[1][0]*q0[1];
        S[1][1] = a0[1]*S[1][1] + k0[1]*v01;  ob1 = S[1][1]*q0[1];
        #pragma unroll
        for (int j = 2; j < 8; j += 2){
          S[j][0]   = a0[j]*S[j][0]     + k0[j]*v00;    oa0 += S[j][0]*q0[j];
          S[j][1]   = a0[j]*S[j][1]     + k0[j]*v01;    oa1 += S[j][1]*q0[j];
          S[j+1][0] = a0[j+1]*S[j+1][0] + k0[j+1]*v00;  ob0 += S[j+1][0]*q0[j+1];
          S[j+1][1] = a0[j+1]*S[j+1][1] + k0[j+1]*v01;  ob1 += S[j+1][1]*q0[j+1];
        }
        *(float2*)&sO[p][w][half*2+0][2*dg] = make_float2(oa0+ob0, oa1+ob1);
      }
      // ---- tt1 of pair ----
      {
        float oa0, oa1, ob0, ob1;
        S[0][0] = a1[0]*S[0][0] + k1[0]*v10;  oa0 = S[0][0]*q1[0];
        S[0][1] = a1[0]*S[0][1] + k1[0]*v11;  oa1 = S[0][1]*q1[0];
        S[1][0] = a1[1]*S[1][0] + k1[1]*v10;  ob0 = S[1][0]*q1[1];
        S[1][1] = a1[1]*S[1][1] + k1[1]*v11;  ob1 = S[1][1]*q1[1];
        #pragma unroll
        for (int j = 2; j < 8; j += 2){
          S[j][0]   = a1[j]*S[j][0]     + k1[j]*v10;    oa0 += S[j][0]*q1[j];
          S[j][1]   = a1[j]*S[j][1]     + k1[j]*v11;    oa1 += S[j][1]*q1[j];
          S[j+1][0] = a1[j+1]*S[j+1][0] + k1[j+1]*v10;  ob0 += S[j+1][0]*q1[j+1];
          S[j+1][1] = a1[j+1]*S[j+1][1] + k1[j+1]*v11;  ob1 += S[j+1][1]*q1[j+1];
        }
        *(float2*)&sO[p][w][half*2+1][2*dg] = make_float2(oa0+ob0, oa1+ob1);
      }
      ap += 1024; kp += 128; qp += 1024; vp += 1024;
    }
    __syncthreads();
    // reduce 8 wave-partials; double-buffered sO -> next sb writes hit p^1,
    // so no second barrier is needed.
    float o = sO[p][0][rtt][rdd] + sO[p][1][rtt][rdd]
            + sO[p][2][rtt][rdd] + sO[p][3][rtt][rdd]
            + sO[p][4][rtt][rdd] + sO[p][5][rtt][rdd]
            + sO[p][6][rtt][rdd] + sO[p][7][rtt][rdd];
    obase[(size_t)(sb*4 + rtt)*1024 + rdd] = f2bf(o);
  }
}

// ----------------------------- launch -----------------------------
extern "C" void kernel_launch(void* const* d_in, const int* in_sizes, int n_in,
                              void* d_out, int out_size, void* d_ws, size_t ws_size,
                              hipStream_t stream){
  const float* x     = (const float*)d_in[0];
  const float* Wq    = (const float*)d_in[1];
  const float* Wk    = (const float*)d_in[2];
  const float* Wv    = (const float*)d_in[3];
  const float* Qc    = (const float*)d_in[4];
  const float* Vc    = (const float*)d_in[5];
  const float* Wa_w  = (const float*)d_in[6];
  const float* Wa_b  = (const float*)d_in[7];
  const float* Wo    = (const float*)d_in[8];
  const float* gamma = (const float*)d_in[9];
  const float* beta  = (const float*)d_in[10];
  float* out = (float*)d_out;

  char* ws = (char*)d_ws;
  size_t off = 0;
  auto alloc = [&](size_t bytes) -> void* {
    void* p = ws + off; off += (bytes + 255) & ~(size_t)255; return p;
  };
  // R1: xnb (bf16 M*1024) -> obuf (bf16 M*1024)
  char* R1 = (char*)alloc((size_t)M_ * 1024 * 2);
  u16*   xnb  = (u16*)R1;
  u16*   obuf = (u16*)R1;
  // R2: proj (f32 M*704) -> qf (f32 M*512)
  char* R2 = (char*)alloc((size_t)M_ * 704 * 4);
  float* proj = (float*)R2;
  float* qf   = (float*)R2;
  float* Sbuf   = (float*)alloc((size_t)64 * NC_ * 8192 * 4);   // 33.5 MB
  u16*   vfb    = (u16*)alloc((size_t)M_ * 1024 * 2);           // v bf16
  float* alphaf = (float*)alloc((size_t)M_ * 512 * 4);
  float* knf    = (float*)alloc((size_t)M_ * 64 * 4);
  u16*   qlatb  = (u16*)alloc((size_t)M_ * 64 * 2);
  u16*   vlatb  = (u16*)alloc((size_t)M_ * 64 * 2);
  u16*   Wcatb  = (u16*)alloc((size_t)768 * 1024 * 2);          // padded to 768
  u16*   QcTb   = (u16*)alloc((size_t)512 * 64 * 2);
  u16*   VcTb   = (u16*)alloc((size_t)1024 * 64 * 2);
  u16*   Wob    = (u16*)alloc((size_t)1024 * 1024 * 2);
  float* btotp  = (float*)alloc((size_t)64 * NC_ * 64 * 4);
  (void)ws_size; (void)in_sizes; (void)n_in; (void)out_size;

  ln_kernel<<<dim3(M_), dim3(256), 0, stream>>>(x, gamma, beta, xnb);
  prep_weights<<<dim3(7552), dim3(256), 0, stream>>>(
      Wq, Wk, Wv, Wa_w, Qc, Vc, Wo, Wcatb, QcTb, VcTb, Wob);
  // proj = xn @ Wcat^T : (M,704) f32   (B padded to 768 rows, col<704 guard)
  gemm_bf16<<<dim3(M_/128, 6), dim3(256), 0, stream>>>(
      xnb, Wcatb, proj, nullptr, nullptr, 704, 1024);
  split_proj<<<dim3(M_/4), dim3(256), 0, stream>>>(
      proj, Wa_b, qlatb, knf, vlatb, alphaf);
  // v = v_lat @ VcT^T : (M,1024) bf16 out
  gemm_bf16<<<dim3(M_/128, 8), dim3(256), 0, stream>>>(
      vlatb, VcTb, nullptr, nullptr, vfb, 1024, 64);
  // q = q_lat @ QcT^T : (M,512) f32 into R2 (proj dead after split_proj)
  gemm_bf16<<<dim3(M_/128, 4), dim3(256), 0, stream>>>(
      qlatb, QcTb, qf, nullptr, nullptr, 512, 64);
  scan_pass1<<<dim3(NC_-1, 64), dim3(512), 0, stream>>>(
      knf, vfb, alphaf, Sbuf, btotp);
  scan_combine<<<dim3(32, 64), dim3(256), 0, stream>>>(Sbuf, btotp);
  scan_pass2<<<dim3(NC_, 64), dim3(512), 0, stream>>>(
      qf, knf, vfb, alphaf, Sbuf, obuf);
  gemm_bf16<<<dim3(M_/128, 8), dim3(256), 0, stream>>>(
      obuf, Wob, out, x, nullptr, 1024, 1024);
}

// Round 6
// 464.073 us; speedup vs baseline: 1.2234x; 1.0990x over previous
//
#include <hip/hip_runtime.h>

typedef unsigned short u16;
typedef unsigned int   u32;
typedef __bf16 bf16x8 __attribute__((ext_vector_type(8)));
typedef float  f32x4  __attribute__((ext_vector_type(4)));
typedef float  f32x8  __attribute__((ext_vector_type(8)));

#define B_  8
#define T_  2048
#define D_  1024
#define H_  8
#define C_  64
#define DV_ 128
#define M_  (B_*T_)   // 16384
#define L_  128       // scan chunk length
#define NC_ (T_/L_)   // 16 chunks

__device__ __forceinline__ u16 f2bf(float f){
  u32 u = __float_as_uint(f);
  u32 r = (u + 0x7fffu + ((u >> 16) & 1u)) >> 16;   // RNE
  return (u16)r;
}
__device__ __forceinline__ float bf2f(u16 u){
  return __uint_as_float(((u32)u) << 16);
}

// async global->LDS, 16B per lane; LDS dest is wave-uniform base + lane*16
typedef const __attribute__((address_space(1))) unsigned int* gp1_t;
typedef __attribute__((address_space(3))) unsigned int* lp3_t;
__device__ __forceinline__ void stage16(const void* g, void* l){
  __builtin_amdgcn_global_load_lds((gp1_t)g, (lp3_t)l, 16, 0, 0);
}

// counted-vmcnt + raw barrier (T3/T4): immediate N, memory-fenced both sides
#define VMCNT(N) asm volatile("s_waitcnt vmcnt(" #N ")" ::: "memory")
#define SBAR() do{ asm volatile("" ::: "memory"); \
                   __builtin_amdgcn_sched_barrier(0); \
                   __builtin_amdgcn_s_barrier(); \
                   __builtin_amdgcn_sched_barrier(0); \
                   asm volatile("" ::: "memory"); }while(0)

// ---------------- LayerNorm: x (M,1024) f32 -> xn bf16 ----------------
__global__ __launch_bounds__(256) void ln_kernel(
    const float* __restrict__ x, const float* __restrict__ gamma,
    const float* __restrict__ beta, u16* __restrict__ xnb){
  const int m = blockIdx.x;
  const int tid = threadIdx.x;
  const int wave = tid >> 6, lane = tid & 63;
  const float* xr = x + (size_t)m * D_;
  float4 xv = *(const float4*)&xr[tid*4];
  float s = xv.x + xv.y + xv.z + xv.w;
  #pragma unroll
  for (int off = 32; off > 0; off >>= 1) s += __shfl_xor(s, off, 64);
  __shared__ float red[8];
  if (lane == 0) red[wave] = s;
  __syncthreads();
  float mu = (red[0]+red[1]+red[2]+red[3]) * (1.f/1024.f);
  float dx = xv.x-mu, dy = xv.y-mu, dz = xv.z-mu, dw = xv.w-mu;
  float ss = dx*dx + dy*dy + dz*dz + dw*dw;
  #pragma unroll
  for (int off = 32; off > 0; off >>= 1) ss += __shfl_xor(ss, off, 64);
  if (lane == 0) red[4+wave] = ss;
  __syncthreads();
  float var = (red[4]+red[5]+red[6]+red[7]) * (1.f/1024.f);
  float rs = rsqrtf(var + 1e-5f);
  float4 g  = *(const float4*)&gamma[tid*4];
  float4 bb = *(const float4*)&beta[tid*4];
  ushort4 o4;
  o4.x = f2bf(dx*rs*g.x + bb.x);
  o4.y = f2bf(dy*rs*g.y + bb.y);
  o4.z = f2bf(dz*rs*g.z + bb.z);
  o4.w = f2bf(dw*rs*g.w + bb.w);
  *(ushort4*)&xnb[(size_t)m*D_ + tid*4] = o4;
}

// ------------- weight prep: convert/concat/transpose to bf16 -------------
// Wcat is padded to 768 rows (zeros in 704..767) so the 128-wide GEMM B-tiles
// never read OOB.
__global__ __launch_bounds__(256) void prep_weights(
    const float* __restrict__ Wq, const float* __restrict__ Wk,
    const float* __restrict__ Wv, const float* __restrict__ Wa,
    const float* __restrict__ Qc, const float* __restrict__ Vc,
    const float* __restrict__ Wo,
    u16* __restrict__ Wcatb, u16* __restrict__ QcTb,
    u16* __restrict__ VcTb,  u16* __restrict__ Wob){
  int idx = blockIdx.x * 256 + threadIdx.x;
  if (idx < 786432){                       // 768*1024 (padded)
    int r = idx >> 10, col = idx & 1023;
    float v = 0.f;
    if (r < 64)       v = Wq[(size_t)r*1024 + col];
    else if (r < 128) v = Wk[(size_t)(r-64)*1024 + col];
    else if (r < 192) v = Wv[(size_t)(r-128)*1024 + col];
    else if (r < 704) v = Wa[(size_t)(r-192)*1024 + col];
    Wcatb[idx] = f2bf(v);
  } else if (idx < 819200){                // +512*64
    int i = idx - 786432;
    int n = i >> 6, c = i & 63; int h = n >> 6, e = n & 63;
    QcTb[i] = f2bf(Qc[((size_t)h*64 + c)*64 + e]);
  } else if (idx < 884736){                // +1024*64
    int i = idx - 819200;
    int n = i >> 6, c = i & 63; int h = n >> 7, d = n & 127;
    VcTb[i] = f2bf(Vc[((size_t)h*64 + c)*128 + d]);
  } else {                                 // +1024*1024 (grid = exact bound)
    int i = idx - 884736;
    Wob[i] = f2bf(Wo[i]);
  }
}

// ---- bf16 MFMA GEMM: C[M,N] = A[M,K] @ Bw[Nr,K]^T (+res) ----
// 128x128 tile, 4 waves (2x2), each wave 64x64 = 4x4 fragments, BK=32.
// K-loop: triple-buffered LDS, counted vmcnt (round-5, kept).
// ROUND-6 CHANGE — COALESCED EPILOGUE: rounds 2-5 all landed at ~125-138us
// with identical scattered-4B epilogues; 134MB of the final GEMM's 156MB
// traffic is res-read + C-write moving at ~1.25 TB/s (64B segments).
// Now: stage the C-tile through LDS (64 rows/pass, rows padded to 132 f32
// -> ds_write conflicts 2-way = free), then all 256 threads stream float4 /
// ushort4 rows: 512B contiguous segments for C store AND res read.
__global__ __launch_bounds__(256) void gemm_bf16(
    const u16* __restrict__ A, const u16* __restrict__ Bw,
    float* __restrict__ C, const float* __restrict__ res,
    u16* __restrict__ Cb, int N, int K){
  // flat LDS: 3 buffers x (A 4096 u16 + B 4096 u16) = 48KB; epilogue reuses
  // the same storage as float sC[64][132] (33.8KB)
  __shared__ __align__(16) u16 SM[3*8192];
  const int tid = threadIdx.x;
  const int wave = tid >> 6;
  const int lane = tid & 63;
  const int q  = lane >> 4;
  const int mr = lane & 15;
  const int wr = wave >> 1, wc = wave & 1;
  const int m0 = blockIdx.x * 128;
  const int n0 = blockIdx.y * 128;

  // staging: inst j covers tile rows [16j,16j+16); wave issues j={2w,2w+1}
  // for A and B. lane -> row lr=lane>>2, LDS 16B-slot lane&3; global chunk
  // pre-swizzled: slg = (lane&3) ^ ((lr>>1)&3)   (T21 involution)
  const int j0 = wave*2;
  const int lr = lane >> 2;
  const int slg = ((lane & 3) ^ ((lr >> 1) & 3)) * 8;
  const u16* pa0 = A  + (size_t)(m0 + (j0  )*16 + lr)*K + slg;
  const u16* pa1 = A  + (size_t)(m0 + (j0+1)*16 + lr)*K + slg;
  const u16* pb0 = Bw + (size_t)(n0 + (j0  )*16 + lr)*K + slg;
  const u16* pb1 = Bw + (size_t)(n0 + (j0+1)*16 + lr)*K + slg;

  union FragU { uint4 u4; bf16x8 v; };
  f32x4 zero = {0.f, 0.f, 0.f, 0.f};
  f32x4 acc[4][4];
  #pragma unroll
  for (int i = 0; i < 4; i++)
    #pragma unroll
    for (int j = 0; j < 4; j++) acc[i][j] = zero;

  // fragment read: row (wr*64+mt*16+mr), 16B-chunk q ^ ((mr>>1)&3)
  const int qs = (q ^ ((mr >> 1) & 3)) * 8;
  const int aoff = (wr*64 + mr)*32 + qs;   // + mt*512
  const int boff = (wc*64 + mr)*32 + qs;

  auto stage_tile = [&](int t, int b){
    int off = t*32;
    u16* Ab = SM + b*8192;
    u16* Bb = SM + b*8192 + 4096;
    stage16(pa0 + off, Ab + (j0  )*512);
    stage16(pa1 + off, Ab + (j0+1)*512);
    stage16(pb0 + off, Bb + (j0  )*512);
    stage16(pb1 + off, Bb + (j0+1)*512);
  };
  auto compute = [&](int b){
    const u16* Ab = SM + b*8192;
    const u16* Bb = SM + b*8192 + 4096;
    bf16x8 afr[4], bfr[4];
    #pragma unroll
    for (int mt = 0; mt < 4; mt++){
      FragU f; f.u4 = *(const uint4*)(Ab + aoff + mt*512);
      afr[mt] = f.v;
    }
    #pragma unroll
    for (int nt2 = 0; nt2 < 4; nt2++){
      FragU f; f.u4 = *(const uint4*)(Bb + boff + nt2*512);
      bfr[nt2] = f.v;
    }
    #pragma unroll
    for (int mt = 0; mt < 4; mt++)
      #pragma unroll
      for (int nt2 = 0; nt2 < 4; nt2++)
        acc[mt][nt2] = __builtin_amdgcn_mfma_f32_16x16x32_bf16(
            afr[mt], bfr[nt2], acc[mt][nt2], 0, 0, 0);
  };

  const int nt = K >> 5;                  // K-tiles (>=2 for all our calls)
  // prologue: tiles 0,1 in flight
  stage_tile(0, 0);
  if (nt > 1) stage_tile(1, 1);

  int bcur = 0;   // buffer holding tile i
  int bst  = 2;   // buffer receiving tile i+2
  for (int i = 0; i < nt-2; i++){
    stage_tile(i+2, bst);
    VMCNT(8);                 // tiles i+1,i+2 may stay in flight; tile i done
    SBAR();
    compute(bcur);
    SBAR();                   // all waves done reading buf bcur
    bcur = (bcur == 2) ? 0 : bcur + 1;
    bst  = (bst  == 2) ? 0 : bst  + 1;
  }
  if (nt >= 2){
    VMCNT(4);                 // tile nt-1 may stay in flight; tile nt-2 done
    SBAR();
    compute(bcur);
    SBAR();
    bcur = (bcur == 2) ? 0 : bcur + 1;
  }
  VMCNT(0);
  SBAR();
  compute(bcur);

  // ---------------- coalesced epilogue via LDS ----------------
  __syncthreads();            // all waves done with LDS staging buffers
  float* sC = (float*)SM;     // [64][132] f32 = 33.8KB
  const int SCW = 132;
  #pragma unroll
  for (int h = 0; h < 2; h++){
    if (wr == h){
      #pragma unroll
      for (int mt = 0; mt < 4; mt++)
        #pragma unroll
        for (int nt2 = 0; nt2 < 4; nt2++)
          #pragma unroll
          for (int r = 0; r < 4; r++)
            sC[(mt*16 + q*4 + r)*SCW + wc*64 + nt2*16 + mr] = acc[mt][nt2][r];
    }
    __syncthreads();
    #pragma unroll
    for (int i = 0; i < 8; i++){
      int idx  = i*256 + tid;      // 0..2047
      int lrow = idx >> 5;         // 0..63
      int c4   = (idx & 31) * 4;   // 0..124
      int grow = m0 + h*64 + lrow;
      int gcol = n0 + c4;
      if (gcol < N){               // N%4==0 for all our calls
        float4 v4 = *(float4*)&sC[lrow*SCW + c4];
        size_t gi = (size_t)grow * N + gcol;
        if (res){
          const float4 rv = *(const float4*)&res[gi];
          v4.x += rv.x; v4.y += rv.y; v4.z += rv.z; v4.w += rv.w;
        }
        if (Cb){
          ushort4 o4 = { f2bf(v4.x), f2bf(v4.y), f2bf(v4.z), f2bf(v4.w) };
          *(ushort4*)&Cb[gi] = o4;
        } else {
          *(float4*)&C[gi] = v4;
        }
      }
    }
    if (h == 0) __syncthreads();   // sC fully read before pass-1 overwrite
  }
}

// ------------- split proj (M x 704) -------------
__global__ __launch_bounds__(256) void split_proj(
    const float* __restrict__ proj, const float* __restrict__ Wab,
    u16* __restrict__ qlatb, float* __restrict__ knf,
    u16* __restrict__ vlatb, float* __restrict__ alphaf){
  const int m = blockIdx.x * 4 + (threadIdx.x >> 6);
  const int lane = threadIdx.x & 63;
  const float* pr = proj + (size_t)m * 704;
  qlatb[(size_t)m*64 + lane] = f2bf(pr[lane]);
  float kv = pr[64 + lane];
  float ss = kv * kv;
  #pragma unroll
  for (int off = 32; off > 0; off >>= 1) ss += __shfl_xor(ss, off, 64);
  float nrm = fmaxf(sqrtf(ss), 1e-12f);
  knf[(size_t)m*64 + lane] = kv / nrm;
  vlatb[(size_t)m*64 + lane] = f2bf(pr[128 + lane]);
  #pragma unroll
  for (int j = 0; j < 8; j++){
    int jj = j*64 + lane;
    float av = pr[192 + jj] + Wab[jj];
    alphaf[(size_t)m*512 + jj] = 1.f / (1.f + expf(-av));
  }
}

// ===================== blocked two-pass gated scan =====================
// 512 threads = 8 waves. wave w owns channel slice [8w, 8w+8); lane dg owns
// value columns {2dg, 2dg+1}. a/k/q are wave-uniform -> SGPRs via
// s_load_dwordx8 (2 timesteps per lgkmcnt(0) to amortize SMEM latency).

__global__ __launch_bounds__(512, 8) void scan_pass1(
    const float* __restrict__ knf, const u16* __restrict__ vb,
    const float* __restrict__ alphaf,
    float* __restrict__ Sbuf, float* __restrict__ btot){
  const int ch = blockIdx.x;        // 0..NC_-2 (last chunk's state unused)
  const int bh = blockIdx.y;
  const int b = bh >> 3, h = bh & 7;
  const int tid = threadIdx.x;
  const int w = __builtin_amdgcn_readfirstlane(tid >> 6);  // wave = ch-group
  const int dg = tid & 63;
  const int t0 = ch * L_;

  const float* kp  = knf    + ((size_t)(b*T_ + t0))*64  + w*8;
  const float* ap  = alphaf + ((size_t)(b*T_ + t0))*512 + h*64 + w*8;
  const float* alp = ap + (dg & 7);            // per-lane alpha for btot
  const u32*   vp  = (const u32*)(vb + ((size_t)(b*T_ + t0))*1024 + h*128) + dg;

  float S[8][2];
  #pragma unroll
  for (int j = 0; j < 8; j++){ S[j][0] = 0.f; S[j][1] = 0.f; }
  float bt = 1.f;

  for (int t = 0; t < L_; t += 2){
    f32x8 a0, a1, k0, k1;
    asm volatile(
      "s_load_dwordx8 %0, %4, 0x0\n\t"
      "s_load_dwordx8 %1, %4, 0x800\n\t"
      "s_load_dwordx8 %2, %5, 0x0\n\t"
      "s_load_dwordx8 %3, %5, 0x100\n\t"
      "s_waitcnt lgkmcnt(0)"
      : "=&s"(a0), "=&s"(a1), "=&s"(k0), "=&s"(k1)
      : "s"(ap), "s"(kp));
    float al0 = alp[0], al1 = alp[512];
    u32 vv0 = vp[0], vv1 = vp[512];
    float v00 = __uint_as_float(vv0 << 16);
    float v01 = __uint_as_float(vv0 & 0xffff0000u);
    float v10 = __uint_as_float(vv1 << 16);
    float v11 = __uint_as_float(vv1 & 0xffff0000u);
    #pragma unroll
    for (int j = 0; j < 8; j++){
      S[j][0] = a0[j]*S[j][0] + k0[j]*v00;
      S[j][1] = a0[j]*S[j][1] + k0[j]*v01;
    }
    bt *= al0;
    #pragma unroll
    for (int j = 0; j < 8; j++){
      S[j][0] = a1[j]*S[j][0] + k1[j]*v10;
      S[j][1] = a1[j]*S[j][1] + k1[j]*v11;
    }
    bt *= al1;
    ap += 1024; kp += 128; alp += 1024; vp += 1024;
  }

  float* Sl = Sbuf + ((size_t)bh*NC_ + ch) * (64*128);
  #pragma unroll
  for (int j = 0; j < 8; j++)
    *(float2*)&Sl[(size_t)(w*8+j)*128 + 2*dg] = make_float2(S[j][0], S[j][1]);
  if (dg < 8) btot[((size_t)bh*NC_ + ch)*64 + w*8 + dg] = bt;
}

// in-place: Sbuf[ch] (local states) -> Sbuf[ch] (prefix init states)
// element-parallel: grid (32, 64), one element per thread, serial over chunks
__global__ __launch_bounds__(256) void scan_combine(
    float* __restrict__ Sbuf, const float* __restrict__ btot){
  const int bh = blockIdx.y;
  const int e  = blockIdx.x * 256 + threadIdx.x;   // 0..8191
  float*       Sb  = Sbuf + (size_t)bh*NC_*8192 + e;
  const float* btb = btot + (size_t)bh*NC_*64 + (e >> 7);
  float S = 0.f;
  #pragma unroll
  for (int j = 0; j < NC_; j++){
    float loc = Sb[(size_t)j*8192];
    Sb[(size_t)j*8192] = S;
    if (j < NC_-1) S = btb[j*64] * S + loc;
  }
}

__global__ __launch_bounds__(512, 8) void scan_pass2(
    const float* __restrict__ qf, const float* __restrict__ knf,
    const u16* __restrict__ vb, const float* __restrict__ alphaf,
    const float* __restrict__ Sbuf, u16* __restrict__ ob){
  const int ch = blockIdx.x;        // 0..NC_-1
  const int bh = blockIdx.y;
  const int b = bh >> 3, h = bh & 7;
  const int tid = threadIdx.x;
  const int w = __builtin_amdgcn_readfirstlane(tid >> 6);  // wave = ch-group
  const int dg = tid & 63;
  const int t0 = ch * L_;
  __shared__ __align__(16) float sO[2][8][4][128];   // 32 KB, double-buffered

  const float* qp = qf     + ((size_t)(b*T_ + t0))*512 + h*64 + w*8;
  const float* kp = knf    + ((size_t)(b*T_ + t0))*64  + w*8;
  const float* ap = alphaf + ((size_t)(b*T_ + t0))*512 + h*64 + w*8;
  const u32*   vp = (const u32*)(vb + ((size_t)(b*T_ + t0))*1024 + h*128) + dg;
  u16* obase = ob + ((size_t)(b*T_ + t0))*1024 + h*128;

  float S[8][2];
  const float* Si = Sbuf + ((size_t)bh*NC_ + ch) * (64*128);
  #pragma unroll
  for (int j = 0; j < 8; j++){
    float2 s2 = *(const float2*)&Si[(size_t)(w*8+j)*128 + 2*dg];
    S[j][0] = s2.x; S[j][1] = s2.y;
  }

  const int rtt = tid >> 7, rdd = tid & 127;   // reduction mapping (4tt x 128d)

  for (int sb = 0; sb < L_/4; sb++){
    const int p = sb & 1;
    #pragma unroll
    for (int half = 0; half < 2; half++){
      f32x8 a0, a1, k0, k1, q0, q1;
      asm volatile(
        "s_load_dwordx8 %0, %6, 0x0\n\t"
        "s_load_dwordx8 %1, %6, 0x800\n\t"
        "s_load_dwordx8 %2, %7, 0x0\n\t"
        "s_load_dwordx8 %3, %7, 0x100\n\t"
        "s_load_dwordx8 %4, %8, 0x0\n\t"
        "s_load_dwordx8 %5, %8, 0x800\n\t"
        "s_waitcnt lgkmcnt(0)"
        : "=&s"(a0), "=&s"(a1), "=&s"(k0), "=&s"(k1), "=&s"(q0), "=&s"(q1)
        : "s"(ap), "s"(kp), "s"(qp));
      u32 vv0 = vp[0], vv1 = vp[512];
      float v00 = __uint_as_float(vv0 << 16);
      float v01 = __uint_as_float(vv0 & 0xffff0000u);
      float v10 = __uint_as_float(vv1 << 16);
      float v11 = __uint_as_float(vv1 & 0xffff0000u);
      // ---- tt0 of pair ----
      {
        float oa0, oa1, ob0, ob1;          // 2 accum chains per column
        S[0][0] = a0[0]*S[0][0] + k0[0]*v00;  oa0 = S[0][0]*q0[0];
        S[0][1] = a0[0]*S[0][1] + k0[0]*v01;  oa1 = S[0][1]*q0[0];
        S[1][0] = a0[1]*S[1][0] + k0[1]*v00;  ob0 = S[1][0]*q0[1];
        S[1][1] = a0[1]*S[1][1] + k0[1]*v01;  ob1 = S[1][1]*q0[1];
        #pragma unroll
        for (int j = 2; j < 8; j += 2){
          S[j][0]   = a0[j]*S[j][0]     + k0[j]*v00;    oa0 += S[j][0]*q0[j];
          S[j][1]   = a0[j]*S[j][1]     + k0[j]*v01;    oa1 += S[j][1]*q0[j];
          S[j+1][0] = a0[j+1]*S[j+1][0] + k0[j+1]*v00;  ob0 += S[j+1][0]*q0[j+1];
          S[j+1][1] = a0[j+1]*S[j+1][1] + k0[j+1]*v01;  ob1 += S[j+1][1]*q0[j+1];
        }
        *(float2*)&sO[p][w][half*2+0][2*dg] = make_float2(oa0+ob0, oa1+ob1);
      }
      // ---- tt1 of pair ----
      {
        float oa0, oa1, ob0, ob1;
        S[0][0] = a1[0]*S[0][0] + k1[0]*v10;  oa0 = S[0][0]*q1[0];
        S[0][1] = a1[0]*S[0][1] + k1[0]*v11;  oa1 = S[0][1]*q1[0];
        S[1][0] = a1[1]*S[1][0] + k1[1]*v10;  ob0 = S[1][0]*q1[1];
        S[1][1] = a1[1]*S[1][1] + k1[1]*v11;  ob1 = S[1][1]*q1[1];
        #pragma unroll
        for (int j = 2; j < 8; j += 2){
          S[j][0]   = a1[j]*S[j][0]     + k1[j]*v10;    oa0 += S[j][0]*q1[j];
          S[j][1]   = a1[j]*S[j][1]     + k1[j]*v11;    oa1 += S[j][1]*q1[j];
          S[j+1][0] = a1[j+1]*S[j+1][0] + k1[j+1]*v10;  ob0 += S[j+1][0]*q1[j+1];
          S[j+1][1] = a1[j+1]*S[j+1][1] + k1[j+1]*v11;  ob1 += S[j+1][1]*q1[j+1];
        }
        *(float2*)&sO[p][w][half*2+1][2*dg] = make_float2(oa0+ob0, oa1+ob1);
      }
      ap += 1024; kp += 128; qp += 1024; vp += 1024;
    }
    __syncthreads();
    // reduce 8 wave-partials; double-buffered sO -> next sb writes hit p^1,
    // so no second barrier is needed.
    float o = sO[p][0][rtt][rdd] + sO[p][1][rtt][rdd]
            + sO[p][2][rtt][rdd] + sO[p][3][rtt][rdd]
            + sO[p][4][rtt][rdd] + sO[p][5][rtt][rdd]
            + sO[p][6][rtt][rdd] + sO[p][7][rtt][rdd];
    obase[(size_t)(sb*4 + rtt)*1024 + rdd] = f2bf(o);
  }
}

// ----------------------------- launch -----------------------------
extern "C" void kernel_launch(void* const* d_in, const int* in_sizes, int n_in,
                              void* d_out, int out_size, void* d_ws, size_t ws_size,
                              hipStream_t stream){
  const float* x     = (const float*)d_in[0];
  const float* Wq    = (const float*)d_in[1];
  const float* Wk    = (const float*)d_in[2];
  const float* Wv    = (const float*)d_in[3];
  const float* Qc    = (const float*)d_in[4];
  const float* Vc    = (const float*)d_in[5];
  const float* Wa_w  = (const float*)d_in[6];
  const float* Wa_b  = (const float*)d_in[7];
  const float* Wo    = (const float*)d_in[8];
  const float* gamma = (const float*)d_in[9];
  const float* beta  = (const float*)d_in[10];
  float* out = (float*)d_out;

  char* ws = (char*)d_ws;
  size_t off = 0;
  auto alloc = [&](size_t bytes) -> void* {
    void* p = ws + off; off += (bytes + 255) & ~(size_t)255; return p;
  };
  // R1: xnb (bf16 M*1024) -> obuf (bf16 M*1024)
  char* R1 = (char*)alloc((size_t)M_ * 1024 * 2);
  u16*   xnb  = (u16*)R1;
  u16*   obuf = (u16*)R1;
  // R2: proj (f32 M*704) -> qf (f32 M*512)
  char* R2 = (char*)alloc((size_t)M_ * 704 * 4);
  float* proj = (float*)R2;
  float* qf   = (float*)R2;
  float* Sbuf   = (float*)alloc((size_t)64 * NC_ * 8192 * 4);   // 33.5 MB
  u16*   vfb    = (u16*)alloc((size_t)M_ * 1024 * 2);           // v bf16
  float* alphaf = (float*)alloc((size_t)M_ * 512 * 4);
  float* knf    = (float*)alloc((size_t)M_ * 64 * 4);
  u16*   qlatb  = (u16*)alloc((size_t)M_ * 64 * 2);
  u16*   vlatb  = (u16*)alloc((size_t)M_ * 64 * 2);
  u16*   Wcatb  = (u16*)alloc((size_t)768 * 1024 * 2);          // padded to 768
  u16*   QcTb   = (u16*)alloc((size_t)512 * 64 * 2);
  u16*   VcTb   = (u16*)alloc((size_t)1024 * 64 * 2);
  u16*   Wob    = (u16*)alloc((size_t)1024 * 1024 * 2);
  float* btotp  = (float*)alloc((size_t)64 * NC_ * 64 * 4);
  (void)ws_size; (void)in_sizes; (void)n_in; (void)out_size;

  ln_kernel<<<dim3(M_), dim3(256), 0, stream>>>(x, gamma, beta, xnb);
  prep_weights<<<dim3(7552), dim3(256), 0, stream>>>(
      Wq, Wk, Wv, Wa_w, Qc, Vc, Wo, Wcatb, QcTb, VcTb, Wob);
  // proj = xn @ Wcat^T : (M,704) f32   (B padded to 768 rows, col<704 guard)
  gemm_bf16<<<dim3(M_/128, 6), dim3(256), 0, stream>>>(
      xnb, Wcatb, proj, nullptr, nullptr, 704, 1024);
  split_proj<<<dim3(M_/4), dim3(256), 0, stream>>>(
      proj, Wa_b, qlatb, knf, vlatb, alphaf);
  // v = v_lat @ VcT^T : (M,1024) bf16 out
  gemm_bf16<<<dim3(M_/128, 8), dim3(256), 0, stream>>>(
      vlatb, VcTb, nullptr, nullptr, vfb, 1024, 64);
  // q = q_lat @ QcT^T : (M,512) f32 into R2 (proj dead after split_proj)
  gemm_bf16<<<dim3(M_/128, 4), dim3(256), 0, stream>>>(
      qlatb, QcTb, qf, nullptr, nullptr, 512, 64);
  scan_pass1<<<dim3(NC_-1, 64), dim3(512), 0, stream>>>(
      knf, vfb, alphaf, Sbuf, btotp);
  scan_combine<<<dim3(32, 64), dim3(256), 0, stream>>>(Sbuf, btotp);
  scan_pass2<<<dim3(NC_, 64), dim3(512), 0, stream>>>(
      qf, knf, vfb, alphaf, Sbuf, obuf);
  gemm_bf16<<<dim3(M_/128, 8), dim3(256), 0, stream>>>(
      obuf, Wob, out, x, nullptr, 1024, 1024);
}